// Round 2
// baseline (3316.039 us; speedup 1.0000x reference)
//
#include <hip/hip_runtime.h>
#include <cstdint>
#include <cstddef>

#define N_NODES 100000
#define N_EDGES 1600000
#define F_INDIM 128
#define HDIM 256
#define C_OUT 40
#define BN_EPS 1e-5f

typedef unsigned short bf16_t;

__device__ __forceinline__ float bf2f(unsigned int u) {
  return __uint_as_float(u << 16);
}
__device__ __forceinline__ bf16_t f2bf(float f) {
  unsigned int x = __float_as_uint(f);
  return (bf16_t)((x + 0x7fffu + ((x >> 16) & 1u)) >> 16);
}

// ---------------- CSR build ----------------
__global__ void k_hist(const int* __restrict__ dst, int* __restrict__ cnt, int E) {
  for (int e = blockIdx.x * blockDim.x + threadIdx.x; e < E; e += gridDim.x * blockDim.x)
    atomicAdd(&cnt[dst[e]], 1);
}

__global__ __launch_bounds__(1024)
void k_scan(const int* __restrict__ cnt, int* __restrict__ row_ptr, int n) {
  __shared__ int buf[1024];
  __shared__ int carry;
  int tid = threadIdx.x;
  if (tid == 0) carry = 0;
  __syncthreads();
  for (int base = 0; base < n; base += 1024) {
    int i = base + tid;
    int v = (i < n) ? cnt[i] : 0;
    buf[tid] = v;
    __syncthreads();
    for (int off = 1; off < 1024; off <<= 1) {
      int t = (tid >= off) ? buf[tid - off] : 0;
      __syncthreads();
      buf[tid] += t;
      __syncthreads();
    }
    if (i < n) row_ptr[i] = carry + buf[tid] - v;   // exclusive prefix
    __syncthreads();
    if (tid == 1023) carry += buf[1023];
    __syncthreads();
  }
  if (tid == 0) row_ptr[n] = carry;
}

__global__ void k_fill(const int* __restrict__ src, const int* __restrict__ dst,
                       const int* __restrict__ row_ptr, int* __restrict__ cursor,
                       int* __restrict__ csr, int E) {
  for (int e = blockIdx.x * blockDim.x + threadIdx.x; e < E; e += gridDim.x * blockDim.x) {
    int d = dst[e];
    int p = atomicAdd(&cursor[d], 1);
    csr[row_ptr[d] + p] = src[e];
  }
}

__global__ void k_inv(const int* __restrict__ cnt, float* __restrict__ inv, int n) {
  int i = blockIdx.x * blockDim.x + threadIdx.x;
  if (i < n) inv[i] = 1.0f / (float)(cnt[i] > 0 ? cnt[i] : 1);
}

// ---------------- mean aggregation (CSR gather, bf16 features) ----------------
__global__ __launch_bounds__(256)
void k_aggregate(const bf16_t* __restrict__ h, const int* __restrict__ row_ptr,
                 const int* __restrict__ csr, const float* __restrict__ inv_deg,
                 bf16_t* __restrict__ mean) {
  int node = blockIdx.x;
  int j = threadIdx.x;                 // 0..255 feature column
  int beg = row_ptr[node], end = row_ptr[node + 1];
  float acc = 0.f;
  for (int p = beg; p < end; ++p) {
    int s = csr[p];
    acc += bf2f(h[(size_t)s * HDIM + j]);
  }
  mean[(size_t)node * HDIM + j] = f2bf(acc * inv_deg[node]);
}

// ---------------- load/store helpers ----------------
__device__ __forceinline__ void load4(const float* p, float* o) {
  float4 v = *reinterpret_cast<const float4*>(p);
  o[0] = v.x; o[1] = v.y; o[2] = v.z; o[3] = v.w;
}
__device__ __forceinline__ void load4(const bf16_t* p, float* o) {
  uint2 v = *reinterpret_cast<const uint2*>(p);
  o[0] = bf2f(v.x & 0xffffu); o[1] = bf2f(v.x >> 16);
  o[2] = bf2f(v.y & 0xffffu); o[3] = bf2f(v.y >> 16);
}
__device__ __forceinline__ void store1(float* p, float v) { *p = v; }
__device__ __forceinline__ void store1(bf16_t* p, float v) { *p = f2bf(v); }

// ---------------- generic tiled f32 GEMM with fused bias+BN+ReLU ----------------
// C[M,OUT] = act( A0 @ W0^T (+ A1 @ W1^T) + bias ), act = BN(+ReLU) if bn != null
// W row-major [OUT, K] (f32). BN params stride 256: gamma,beta,mean,var.
#define BM 64
#define BN 64
#define BK 16

template <typename TA, typename TOUT>
__global__ __launch_bounds__(256)
void gemm_fused(const TA* __restrict__ A0, const float* __restrict__ W0,
                const TA* __restrict__ A1, const float* __restrict__ W1,
                const float* __restrict__ bias, const float* __restrict__ bn,
                TOUT* __restrict__ C, int M, int K, int OUT) {
  __shared__ float As[BK][BM + 1];
  __shared__ float Bs[BK][BN + 1];
  int row0 = blockIdx.x * BM;
  int col0 = blockIdx.y * BN;
  int tid = threadIdx.x;
  int tx = tid & 15, ty = tid >> 4;
  float acc[4][4] = {};
  int nk = K / BK;
  int nph = (A1 != nullptr) ? 2 : 1;
  for (int ph = 0; ph < nph; ++ph) {
    const TA* A = ph ? A1 : A0;
    const float* W = ph ? W1 : W0;
    for (int kt = 0; kt < nk; ++kt) {
      int k0 = kt * BK;
      // A tile: 64 rows x 16 k, 4 elements per thread
      {
        int m = tid >> 2;
        int kk0 = (tid & 3) * 4;
        int gr = row0 + m;
        float av[4] = {0.f, 0.f, 0.f, 0.f};
        if (gr < M) load4(&A[(size_t)gr * K + k0 + kk0], av);
        As[kk0 + 0][m] = av[0]; As[kk0 + 1][m] = av[1];
        As[kk0 + 2][m] = av[2]; As[kk0 + 3][m] = av[3];
      }
      // W tile (always f32)
      {
        int n = tid >> 2;
        int kk0 = (tid & 3) * 4;
        int gc = col0 + n;
        float wv[4] = {0.f, 0.f, 0.f, 0.f};
        if (gc < OUT) load4(&W[(size_t)gc * K + k0 + kk0], wv);
        Bs[kk0 + 0][n] = wv[0]; Bs[kk0 + 1][n] = wv[1];
        Bs[kk0 + 2][n] = wv[2]; Bs[kk0 + 3][n] = wv[3];
      }
      __syncthreads();
#pragma unroll
      for (int kk = 0; kk < BK; ++kk) {
        float a[4], b[4];
#pragma unroll
        for (int i = 0; i < 4; ++i) a[i] = As[kk][ty * 4 + i];
#pragma unroll
        for (int j = 0; j < 4; ++j) b[j] = Bs[kk][tx * 4 + j];
#pragma unroll
        for (int i = 0; i < 4; ++i)
#pragma unroll
          for (int j = 0; j < 4; ++j)
            acc[i][j] += a[i] * b[j];
      }
      __syncthreads();
    }
  }
  // epilogue
#pragma unroll
  for (int i = 0; i < 4; ++i) {
    int r = row0 + ty * 4 + i;
    if (r >= M) continue;
#pragma unroll
    for (int j = 0; j < 4; ++j) {
      int c = col0 + tx * 4 + j;
      if (c >= OUT) continue;
      float v = acc[i][j] + (bias ? bias[c] : 0.f);
      if (bn) {
        float g = bn[c], bb = bn[256 + c], mm = bn[512 + c], vv = bn[768 + c];
        v = (v - mm) * (g * rsqrtf(vv + BN_EPS)) + bb;
        v = fmaxf(v, 0.f);
      }
      store1(&C[(size_t)r * OUT + c], v);
    }
  }
}

// ---------------- row log-softmax (C=40) ----------------
__global__ __launch_bounds__(256)
void k_logsoftmax(const float* __restrict__ logits, float* __restrict__ out, int M) {
  int row = blockIdx.x * 4 + (threadIdx.x >> 6);
  if (row >= M) return;
  int lane = threadIdx.x & 63;
  float v = (lane < C_OUT) ? logits[(size_t)row * C_OUT + lane] : -1e30f;
  float m = v;
#pragma unroll
  for (int o = 32; o; o >>= 1) m = fmaxf(m, __shfl_xor(m, o));
  float e = (lane < C_OUT) ? expf(v - m) : 0.f;
  float s = e;
#pragma unroll
  for (int o = 32; o; o >>= 1) s += __shfl_xor(s, o);
  if (lane < C_OUT) out[(size_t)row * C_OUT + lane] = v - m - logf(s);
}

// ---------------- host launch ----------------
extern "C" void kernel_launch(void* const* d_in, const int* in_sizes, int n_in,
                              void* d_out, int out_size, void* d_ws, size_t ws_size,
                              hipStream_t stream) {
  const float* x       = (const float*)d_in[0];
  const int*   ei      = (const int*)d_in[1];   // [2, E] int32
  const float* pre_w   = (const float*)d_in[2];
  const float* pre_b   = (const float*)d_in[3];
  const float* bn      = (const float*)d_in[4]; // [5,4,256]
  const float* lin_l_w = (const float*)d_in[5];
  const float* lin_l_b = (const float*)d_in[6];
  const float* lin_r_w = (const float*)d_in[7];
  const float* post1_w = (const float*)d_in[8];
  const float* post1_b = (const float*)d_in[9];
  const float* post2_w = (const float*)d_in[10];
  const float* post2_b = (const float*)d_in[11];
  float* out = (float*)d_out;

  const int* src = ei;
  const int* dstv = ei + N_EDGES;

  char* base = (char*)d_ws;
  size_t off = 0;
  auto alloc = [&](size_t bytes) -> void* {
    void* p = base + off;
    off = (off + bytes + 255) & ~(size_t)255;
    return p;
  };
  bf16_t* hA = (bf16_t*)alloc((size_t)N_NODES * HDIM * 2);
  bf16_t* hB = (bf16_t*)alloc((size_t)N_NODES * HDIM * 2);   // also reused for f32 logits (16MB < 51.2MB)
  bf16_t* hC = (bf16_t*)alloc((size_t)N_NODES * HDIM * 2);
  int* row_ptr = (int*)alloc((size_t)(N_NODES + 1) * 4);
  int* cnt     = (int*)alloc((size_t)N_NODES * 4);
  int* cursor  = (int*)alloc((size_t)N_NODES * 4);
  int* csr     = (int*)alloc((size_t)N_EDGES * 4);
  float* inv   = (float*)alloc((size_t)N_NODES * 4);
  (void)n_in; (void)in_sizes; (void)out_size;
  if (off > ws_size) return;   // workspace too small: leave output zeroed (visible failure, no fault)

  hipMemsetAsync(cnt, 0, (size_t)N_NODES * 4, stream);
  hipMemsetAsync(cursor, 0, (size_t)N_NODES * 4, stream);
  k_hist<<<2048, 256, 0, stream>>>(dstv, cnt, N_EDGES);
  k_scan<<<1, 1024, 0, stream>>>(cnt, row_ptr, N_NODES);
  k_fill<<<2048, 256, 0, stream>>>(src, dstv, row_ptr, cursor, csr, N_EDGES);
  k_inv<<<(N_NODES + 255) / 256, 256, 0, stream>>>(cnt, inv, N_NODES);

  dim3 gH((N_NODES + BM - 1) / BM, HDIM / BN);
  // pre: h = relu(bn0(x @ pre_w^T + pre_b))   (f32 A, bf16 out)
  gemm_fused<float, bf16_t><<<gH, 256, 0, stream>>>(
      x, pre_w, nullptr, nullptr, pre_b, bn, hA, N_NODES, F_INDIM, HDIM);

  bf16_t* hcur = hA;
  bf16_t* hnext = hC;
  for (int i = 0; i < 3; ++i) {
    k_aggregate<<<N_NODES, 256, 0, stream>>>(hcur, row_ptr, csr, inv, hB);
    gemm_fused<bf16_t, bf16_t><<<gH, 256, 0, stream>>>(
        hB, lin_l_w + (size_t)i * HDIM * HDIM,
        hcur, lin_r_w + (size_t)i * HDIM * HDIM,
        lin_l_b + (size_t)i * HDIM,
        bn + (size_t)(i + 1) * 4 * HDIM,
        hnext, N_NODES, HDIM, HDIM);
    bf16_t* t = hcur; hcur = hnext; hnext = t;
  }
  // post1: bf16 in, bf16 out
  gemm_fused<bf16_t, bf16_t><<<gH, 256, 0, stream>>>(
      hcur, post1_w, nullptr, nullptr, post1_b,
      bn + (size_t)4 * 4 * HDIM, hnext, N_NODES, HDIM, HDIM);
  // post2 -> f32 logits into hB region (no bn)
  float* logits = (float*)hB;
  dim3 gC((N_NODES + BM - 1) / BM, 1);
  gemm_fused<bf16_t, float><<<gC, 256, 0, stream>>>(
      hnext, post2_w, nullptr, nullptr, post2_b,
      nullptr, logits, N_NODES, HDIM, C_OUT);
  k_logsoftmax<<<(N_NODES + 3) / 4, 256, 0, stream>>>(logits, out, N_NODES);
}

// Round 5
// 1063.064 us; speedup vs baseline: 3.1193x; 3.1193x over previous
//
#include <hip/hip_runtime.h>
#include <cstdint>
#include <cstddef>

#define N_NODES 100000
#define N_EDGES 1600000
#define F_INDIM 128
#define HDIM 256
#define C_OUT 40
#define BN_EPS 1e-5f

typedef unsigned short bf16_t;
typedef __attribute__((ext_vector_type(8))) short bf16x8;
typedef __attribute__((ext_vector_type(4))) float f32x4;

__device__ __forceinline__ float bf2f(unsigned int u) {
  return __uint_as_float(u << 16);
}
__device__ __forceinline__ bf16_t f2bf(float f) {
  unsigned int x = __float_as_uint(f);
  return (bf16_t)((x + 0x7fffu + ((x >> 16) & 1u)) >> 16);
}

// ---------------- f32 -> bf16 conversion (n % 4 == 0) ----------------
__global__ void k_cvt(const float* __restrict__ s, bf16_t* __restrict__ d, int n) {
  int i = (blockIdx.x * blockDim.x + threadIdx.x) * 4;
  if (i >= n) return;
  float4 v = *reinterpret_cast<const float4*>(&s[i]);
  uint2 o;
  o.x = (unsigned)f2bf(v.x) | ((unsigned)f2bf(v.y) << 16);
  o.y = (unsigned)f2bf(v.z) | ((unsigned)f2bf(v.w) << 16);
  *reinterpret_cast<uint2*>(&d[i]) = o;
}

// ---------------- CSR build ----------------
__global__ void k_hist(const int* __restrict__ dst, int* __restrict__ cnt, int E) {
  for (int e = blockIdx.x * blockDim.x + threadIdx.x; e < E; e += gridDim.x * blockDim.x)
    atomicAdd(&cnt[dst[e]], 1);
}

__global__ __launch_bounds__(1024)
void k_scan_local(const int* __restrict__ cnt, int* __restrict__ row_ptr,
                  int* __restrict__ blk_sum, int n) {
  __shared__ int buf[1024];
  int tid = threadIdx.x;
  int i = blockIdx.x * 1024 + tid;
  int v = (i < n) ? cnt[i] : 0;
  buf[tid] = v;
  __syncthreads();
  for (int off = 1; off < 1024; off <<= 1) {
    int t = (tid >= off) ? buf[tid - off] : 0;
    __syncthreads();
    buf[tid] += t;
    __syncthreads();
  }
  if (i < n) row_ptr[i] = buf[tid] - v;       // block-local exclusive
  if (tid == 1023) blk_sum[blockIdx.x] = buf[1023];
}

__global__ __launch_bounds__(128)
void k_scan_blk(const int* __restrict__ blk_sum, int* __restrict__ blk_off, int nb) {
  __shared__ int buf[128];
  int tid = threadIdx.x;
  int v = (tid < nb) ? blk_sum[tid] : 0;
  buf[tid] = v;
  __syncthreads();
  for (int off = 1; off < 128; off <<= 1) {
    int t = (tid >= off) ? buf[tid - off] : 0;
    __syncthreads();
    buf[tid] += t;
    __syncthreads();
  }
  if (tid < nb) blk_off[tid] = buf[tid] - v;  // exclusive
}

__global__ void k_scan_add(int* __restrict__ row_ptr, const int* __restrict__ blk_off, int n) {
  int i = blockIdx.x * blockDim.x + threadIdx.x;
  if (i < n) row_ptr[i] += blk_off[i >> 10];
  if (i == 0) row_ptr[n] = N_EDGES;
}

__global__ void k_fill(const int* __restrict__ src, const int* __restrict__ dst,
                       const int* __restrict__ row_ptr, int* __restrict__ cursor,
                       int* __restrict__ csr, int E) {
  for (int e = blockIdx.x * blockDim.x + threadIdx.x; e < E; e += gridDim.x * blockDim.x) {
    int d = dst[e];
    int p = atomicAdd(&cursor[d], 1);
    csr[row_ptr[d] + p] = src[e];
  }
}

__global__ void k_inv(const int* __restrict__ cnt, float* __restrict__ inv, int n) {
  int i = blockIdx.x * blockDim.x + threadIdx.x;
  if (i < n) inv[i] = 1.0f / (float)(cnt[i] > 0 ? cnt[i] : 1);
}

// ---------------- mean aggregation: one wave per node, 8B/lane ----------------
__global__ __launch_bounds__(256)
void k_aggregate(const bf16_t* __restrict__ h, const int* __restrict__ row_ptr,
                 const int* __restrict__ csr, const float* __restrict__ inv_deg,
                 bf16_t* __restrict__ mean) {
  int w = threadIdx.x >> 6, lane = threadIdx.x & 63;
  int node = blockIdx.x * 4 + w;
  if (node >= N_NODES) return;
  int beg = row_ptr[node], end = row_ptr[node + 1];
  float a0 = 0.f, a1 = 0.f, a2 = 0.f, a3 = 0.f;
  for (int p = beg; p < end; ++p) {
    int s = csr[p];
    uint2 v = *reinterpret_cast<const uint2*>(&h[(size_t)s * HDIM + lane * 4]);
    a0 += bf2f(v.x & 0xffffu); a1 += bf2f(v.x >> 16);
    a2 += bf2f(v.y & 0xffffu); a3 += bf2f(v.y >> 16);
  }
  float iv = inv_deg[node];
  uint2 o;
  o.x = (unsigned)f2bf(a0 * iv) | ((unsigned)f2bf(a1 * iv) << 16);
  o.y = (unsigned)f2bf(a2 * iv) | ((unsigned)f2bf(a3 * iv) << 16);
  *reinterpret_cast<uint2*>(&mean[(size_t)node * HDIM + lane * 4]) = o;
}

// ---------------- output store helpers ----------------
__device__ __forceinline__ void store1(float* p, float v) { *p = v; }
__device__ __forceinline__ void store1(bf16_t* p, float v) { *p = f2bf(v); }

// ---------------- bf16 MFMA GEMM, fused bias + BN + ReLU ----------------
// C[M,OUT] = act( A0 @ W0^T (+ A1 @ W1^T) + bias ), W row-major [OUT,K] bf16.
// 128x128 block tile, BK=32, 4 waves (2x2), 4x4 fragments of 16x16x32 per wave.
// LDS row stride 40 bf16 (80B): frag ds_read_b128 conflict-free (G4 arithmetic).
#define LDSK 40

template <typename TOUT>
__global__ __launch_bounds__(256)
void gemm_mfma(const bf16_t* __restrict__ A0, const bf16_t* __restrict__ W0,
               const bf16_t* __restrict__ A1, const bf16_t* __restrict__ W1,
               const float* __restrict__ bias, const float* __restrict__ bn,
               TOUT* __restrict__ C, int M, int K, int OUT, int dual) {
  __shared__ bf16_t lds[2][(128 + 128) * LDSK];
  const int tid = threadIdx.x;
  const int lane = tid & 63, wid = tid >> 6;
  const int wm = wid >> 1, wn = wid & 1;
  const int row0 = blockIdx.x * 128, col0 = blockIdx.y * 128;
  const int l15 = lane & 15, l4 = lane >> 4;

  const int srow = tid >> 1;        // staging row 0..127
  const int sk = (tid & 1) * 16;    // staging k-offset (bf16) within BK=32

  const int nk = K / 32;
  const int nsteps = dual ? nk * 2 : nk;

  f32x4 acc[4][4] = {};
  uint4 va0, va1, vb0, vb1;

  auto stage_load = [&](int s) {
    const bf16_t* A = (s < nk) ? A0 : A1;
    const bf16_t* W = (s < nk) ? W0 : W1;
    int kk = ((s < nk) ? s : s - nk) * 32 + sk;
    uint4 z; z.x = z.y = z.z = z.w = 0u;
    va0 = z; va1 = z; vb0 = z; vb1 = z;
    int ar = row0 + srow;
    if (ar < M) {
      const uint4* p = reinterpret_cast<const uint4*>(&A[(size_t)ar * K + kk]);
      va0 = p[0]; va1 = p[1];
    }
    int br = col0 + srow;
    if (br < OUT) {
      const uint4* p = reinterpret_cast<const uint4*>(&W[(size_t)br * K + kk]);
      vb0 = p[0]; vb1 = p[1];
    }
  };
  auto stage_write = [&](int b) {
    uint4* la = reinterpret_cast<uint4*>(&lds[b][srow * LDSK + sk]);
    la[0] = va0; la[1] = va1;
    uint4* lb = reinterpret_cast<uint4*>(&lds[b][(128 + srow) * LDSK + sk]);
    lb[0] = vb0; lb[1] = vb1;
  };

  stage_load(0);
  stage_write(0);
  __syncthreads();
  int cur = 0;
  for (int s = 0; s < nsteps; ++s) {
    if (s + 1 < nsteps) stage_load(s + 1);   // global loads overlap MFMA below
    const bf16_t* pa = &lds[cur][(wm * 64 + l15) * LDSK + l4 * 8];
    const bf16_t* pb = &lds[cur][(128 + wn * 64 + l15) * LDSK + l4 * 8];
    bf16x8 a[4], b[4];
#pragma unroll
    for (int i = 0; i < 4; ++i) a[i] = *reinterpret_cast<const bf16x8*>(&pa[i * 16 * LDSK]);
#pragma unroll
    for (int j = 0; j < 4; ++j) b[j] = *reinterpret_cast<const bf16x8*>(&pb[j * 16 * LDSK]);
#pragma unroll
    for (int i = 0; i < 4; ++i)
#pragma unroll
      for (int j = 0; j < 4; ++j)
        acc[i][j] = __builtin_amdgcn_mfma_f32_16x16x32_bf16(a[i], b[j], acc[i][j], 0, 0, 0);
    if (s + 1 < nsteps) {
      stage_write(cur ^ 1);
      __syncthreads();
      cur ^= 1;
    }
  }

  // epilogue: C/D frag mapping col=lane&15, row=(lane>>4)*4+reg  [m89]
#pragma unroll
  for (int j = 0; j < 4; ++j) {
    int col = col0 + wn * 64 + j * 16 + l15;
    if (col >= OUT) continue;
    float bs = bias ? bias[col] : 0.f;
    float scale = 1.f, shift = bs;
    bool has_bn = (bn != nullptr);
    if (has_bn) {
      float g = bn[col], bb = bn[256 + col], mm = bn[512 + col], vv = bn[768 + col];
      float is = g * rsqrtf(vv + BN_EPS);
      scale = is; shift = (bs - mm) * is + bb;
    }
#pragma unroll
    for (int i = 0; i < 4; ++i) {
#pragma unroll
      for (int r = 0; r < 4; ++r) {
        int row = row0 + wm * 64 + i * 16 + l4 * 4 + r;
        if (row >= M) continue;
        float v = acc[i][j][r];
        v = has_bn ? fmaxf(v * scale + shift, 0.f) : (v + bs);
        store1(&C[(size_t)row * OUT + col], v);
      }
    }
  }
}

// ---------------- row log-softmax (C=40) ----------------
__global__ __launch_bounds__(256)
void k_logsoftmax(const float* __restrict__ logits, float* __restrict__ out, int M) {
  int row = blockIdx.x * 4 + (threadIdx.x >> 6);
  if (row >= M) return;
  int lane = threadIdx.x & 63;
  float v = (lane < C_OUT) ? logits[(size_t)row * C_OUT + lane] : -1e30f;
  float m = v;
#pragma unroll
  for (int o = 32; o; o >>= 1) m = fmaxf(m, __shfl_xor(m, o));
  float e = (lane < C_OUT) ? expf(v - m) : 0.f;
  float s = e;
#pragma unroll
  for (int o = 32; o; o >>= 1) s += __shfl_xor(s, o);
  if (lane < C_OUT) out[(size_t)row * C_OUT + lane] = v - m - logf(s);
}

// ---------------- host launch ----------------
extern "C" void kernel_launch(void* const* d_in, const int* in_sizes, int n_in,
                              void* d_out, int out_size, void* d_ws, size_t ws_size,
                              hipStream_t stream) {
  const float* x       = (const float*)d_in[0];
  const int*   ei      = (const int*)d_in[1];   // [2, E] int32
  const float* pre_w   = (const float*)d_in[2];
  const float* pre_b   = (const float*)d_in[3];
  const float* bn      = (const float*)d_in[4]; // [5,4,256]
  const float* lin_l_w = (const float*)d_in[5];
  const float* lin_l_b = (const float*)d_in[6];
  const float* lin_r_w = (const float*)d_in[7];
  const float* post1_w = (const float*)d_in[8];
  const float* post1_b = (const float*)d_in[9];
  const float* post2_w = (const float*)d_in[10];
  const float* post2_b = (const float*)d_in[11];
  float* out = (float*)d_out;

  const int* src = ei;
  const int* dstv = ei + N_EDGES;

  char* base = (char*)d_ws;
  size_t off = 0;
  auto alloc = [&](size_t bytes) -> void* {
    void* p = base + off;
    off = (off + bytes + 255) & ~(size_t)255;
    return p;
  };
  bf16_t* hA = (bf16_t*)alloc((size_t)N_NODES * HDIM * 2);
  bf16_t* hB = (bf16_t*)alloc((size_t)N_NODES * HDIM * 2);  // also x_bf16 pre-GEMM, f32 logits post
  bf16_t* hC = (bf16_t*)alloc((size_t)N_NODES * HDIM * 2);
  int* row_ptr = (int*)alloc((size_t)(N_NODES + 1) * 4);
  int* cnt     = (int*)alloc((size_t)N_NODES * 4);
  int* cursor  = (int*)alloc((size_t)N_NODES * 4);
  int* csr     = (int*)alloc((size_t)N_EDGES * 4);
  float* inv   = (float*)alloc((size_t)N_NODES * 4);
  int* blk_sum = (int*)alloc(128 * 4);
  int* blk_off = (int*)alloc(128 * 4);
  bf16_t* w_pre = (bf16_t*)alloc((size_t)HDIM * F_INDIM * 2);
  bf16_t* w_ll  = (bf16_t*)alloc((size_t)3 * HDIM * HDIM * 2);
  bf16_t* w_lr  = (bf16_t*)alloc((size_t)3 * HDIM * HDIM * 2);
  bf16_t* w_p1  = (bf16_t*)alloc((size_t)HDIM * HDIM * 2);
  bf16_t* w_p2  = (bf16_t*)alloc((size_t)C_OUT * HDIM * 2);
  (void)n_in; (void)in_sizes; (void)out_size;
  if (off > ws_size) return;  // visible failure (zeros), no fault

  bf16_t* x_bf = hB;

  // weight/input conversions
  {
    int n;
    n = N_NODES * F_INDIM;
    k_cvt<<<(n / 4 + 255) / 256, 256, 0, stream>>>(x, x_bf, n);
    n = HDIM * F_INDIM;
    k_cvt<<<(n / 4 + 255) / 256, 256, 0, stream>>>(pre_w, w_pre, n);
    n = 3 * HDIM * HDIM;
    k_cvt<<<(n / 4 + 255) / 256, 256, 0, stream>>>(lin_l_w, w_ll, n);
    k_cvt<<<(n / 4 + 255) / 256, 256, 0, stream>>>(lin_r_w, w_lr, n);
    n = HDIM * HDIM;
    k_cvt<<<(n / 4 + 255) / 256, 256, 0, stream>>>(post1_w, w_p1, n);
    n = C_OUT * HDIM;
    k_cvt<<<(n / 4 + 255) / 256, 256, 0, stream>>>(post2_w, w_p2, n);
  }

  // CSR build
  hipMemsetAsync(cnt, 0, (size_t)N_NODES * 4, stream);
  hipMemsetAsync(cursor, 0, (size_t)N_NODES * 4, stream);
  k_hist<<<2048, 256, 0, stream>>>(dstv, cnt, N_EDGES);
  int nb = (N_NODES + 1023) / 1024;  // 98
  k_scan_local<<<nb, 1024, 0, stream>>>(cnt, row_ptr, blk_sum, N_NODES);
  k_scan_blk<<<1, 128, 0, stream>>>(blk_sum, blk_off, nb);
  k_scan_add<<<(N_NODES + 255) / 256, 256, 0, stream>>>(row_ptr, blk_off, N_NODES);
  k_fill<<<2048, 256, 0, stream>>>(src, dstv, row_ptr, cursor, csr, N_EDGES);
  k_inv<<<(N_NODES + 255) / 256, 256, 0, stream>>>(cnt, inv, N_NODES);

  dim3 gH((N_NODES + 127) / 128, 2);   // OUT=256
  // pre: h = relu(bn0(x @ pre_w^T + pre_b))
  gemm_mfma<bf16_t><<<gH, 256, 0, stream>>>(
      x_bf, w_pre, nullptr, nullptr, pre_b, bn, hA, N_NODES, F_INDIM, HDIM, 0);

  bf16_t* hcur = hA;
  bf16_t* hnext = hC;
  for (int i = 0; i < 3; ++i) {
    k_aggregate<<<N_NODES / 4, 256, 0, stream>>>(hcur, row_ptr, csr, inv, hB);
    gemm_mfma<bf16_t><<<gH, 256, 0, stream>>>(
        hB, w_ll + (size_t)i * HDIM * HDIM,
        hcur, w_lr + (size_t)i * HDIM * HDIM,
        lin_l_b + (size_t)i * HDIM,
        bn + (size_t)(i + 1) * 4 * HDIM,
        hnext, N_NODES, HDIM, HDIM, 1);
    bf16_t* t = hcur; hcur = hnext; hnext = t;
  }
  // post1
  gemm_mfma<bf16_t><<<gH, 256, 0, stream>>>(
      hcur, w_p1, nullptr, nullptr, post1_b,
      bn + (size_t)4 * 4 * HDIM, hnext, N_NODES, HDIM, HDIM, 0);
  // post2 -> f32 logits (no bn); hB is free now
  float* logits = (float*)hB;
  dim3 gC((N_NODES + 127) / 128, 1);
  gemm_mfma<float><<<gC, 256, 0, stream>>>(
      hnext, w_p2, nullptr, nullptr, post2_b,
      nullptr, logits, N_NODES, HDIM, C_OUT, 0);
  k_logsoftmax<<<(N_NODES + 3) / 4, 256, 0, stream>>>(logits, out, N_NODES);
}

// Round 6
// 884.012 us; speedup vs baseline: 3.7511x; 1.2025x over previous
//
#include <hip/hip_runtime.h>
#include <cstdint>
#include <cstddef>

#define N_NODES 100000
#define N_EDGES 1600000
#define F_INDIM 128
#define HDIM 256
#define C_OUT 40
#define BN_EPS 1e-5f

typedef unsigned short bf16_t;
typedef __attribute__((ext_vector_type(8))) short bf16x8;
typedef __attribute__((ext_vector_type(4))) float f32x4;

__device__ __forceinline__ float bf2f(unsigned int u) {
  return __uint_as_float(u << 16);
}
__device__ __forceinline__ bf16_t f2bf(float f) {
  unsigned int x = __float_as_uint(f);
  return (bf16_t)((x + 0x7fffu + ((x >> 16) & 1u)) >> 16);
}

// ---------------- f32 -> bf16 conversion (n % 4 == 0) ----------------
__global__ void k_cvt(const float* __restrict__ s, bf16_t* __restrict__ d, int n) {
  int i = (blockIdx.x * blockDim.x + threadIdx.x) * 4;
  if (i >= n) return;
  float4 v = *reinterpret_cast<const float4*>(&s[i]);
  uint2 o;
  o.x = (unsigned)f2bf(v.x) | ((unsigned)f2bf(v.y) << 16);
  o.y = (unsigned)f2bf(v.z) | ((unsigned)f2bf(v.w) << 16);
  *reinterpret_cast<uint2*>(&d[i]) = o;
}

// ---------------- CSR build ----------------
__global__ void k_hist(const int* __restrict__ dst, int* __restrict__ cnt, int E) {
  for (int e = blockIdx.x * blockDim.x + threadIdx.x; e < E; e += gridDim.x * blockDim.x)
    atomicAdd(&cnt[dst[e]], 1);
}

__global__ __launch_bounds__(1024)
void k_scan_local(const int* __restrict__ cnt, int* __restrict__ row_ptr,
                  int* __restrict__ blk_sum, int n) {
  __shared__ int buf[1024];
  int tid = threadIdx.x;
  int i = blockIdx.x * 1024 + tid;
  int v = (i < n) ? cnt[i] : 0;
  buf[tid] = v;
  __syncthreads();
  for (int off = 1; off < 1024; off <<= 1) {
    int t = (tid >= off) ? buf[tid - off] : 0;
    __syncthreads();
    buf[tid] += t;
    __syncthreads();
  }
  if (i < n) row_ptr[i] = buf[tid] - v;       // block-local exclusive
  if (tid == 1023) blk_sum[blockIdx.x] = buf[1023];
}

__global__ __launch_bounds__(128)
void k_scan_blk(const int* __restrict__ blk_sum, int* __restrict__ blk_off, int nb) {
  __shared__ int buf[128];
  int tid = threadIdx.x;
  int v = (tid < nb) ? blk_sum[tid] : 0;
  buf[tid] = v;
  __syncthreads();
  for (int off = 1; off < 128; off <<= 1) {
    int t = (tid >= off) ? buf[tid - off] : 0;
    __syncthreads();
    buf[tid] += t;
    __syncthreads();
  }
  if (tid < nb) blk_off[tid] = buf[tid] - v;  // exclusive
}

__global__ void k_scan_add(int* __restrict__ row_ptr, const int* __restrict__ blk_off, int n) {
  int i = blockIdx.x * blockDim.x + threadIdx.x;
  if (i < n) row_ptr[i] += blk_off[i >> 10];
  if (i == 0) row_ptr[n] = N_EDGES;
}

__global__ void k_fill(const int* __restrict__ src, const int* __restrict__ dst,
                       const int* __restrict__ row_ptr, int* __restrict__ cursor,
                       int* __restrict__ csr, int E) {
  for (int e = blockIdx.x * blockDim.x + threadIdx.x; e < E; e += gridDim.x * blockDim.x) {
    int d = dst[e];
    int p = atomicAdd(&cursor[d], 1);
    csr[row_ptr[d] + p] = src[e];
  }
}

__global__ void k_inv(const int* __restrict__ cnt, float* __restrict__ inv, int n) {
  int i = blockIdx.x * blockDim.x + threadIdx.x;
  if (i < n) inv[i] = 1.0f / (float)(cnt[i] > 0 ? cnt[i] : 1);
}

// ---------------- mean aggregation ----------------
// One wave per node. Half-wave (32 lanes x 16B) covers one 512B feature row,
// so a wave processes 2 edges per step; manual x2 unroll keeps 4 row-loads
// (plus index loads) in flight. Cross-half combine via shfl_xor(32).
__device__ __forceinline__ void add8(float* acc, uint4 r) {
  acc[0] += bf2f(r.x & 0xffffu); acc[1] += bf2f(r.x >> 16);
  acc[2] += bf2f(r.y & 0xffffu); acc[3] += bf2f(r.y >> 16);
  acc[4] += bf2f(r.z & 0xffffu); acc[5] += bf2f(r.z >> 16);
  acc[6] += bf2f(r.w & 0xffffu); acc[7] += bf2f(r.w >> 16);
}

__global__ __launch_bounds__(256)
void k_aggregate(const bf16_t* __restrict__ h, const int* __restrict__ row_ptr,
                 const int* __restrict__ csr, const float* __restrict__ inv_deg,
                 bf16_t* __restrict__ mean) {
  int w = threadIdx.x >> 6, lane = threadIdx.x & 63;
  int node = blockIdx.x * 4 + w;
  if (node >= N_NODES) return;
  int beg = row_ptr[node], end = row_ptr[node + 1];
  int half = lane >> 5;         // 0 or 1: which edge of the pair
  int l32 = lane & 31;          // 16B column block within the row
  float acc[8] = {};
  int deg = end - beg;
  int p = beg;
  int p4 = beg + (deg & ~3);
  for (; p < p4; p += 4) {       // 4 edges per iteration, 2 row loads/lane in flight
    int s0 = csr[p + half];
    int s1 = csr[p + 2 + half];
    uint4 r0 = *reinterpret_cast<const uint4*>(&h[(size_t)s0 * HDIM + l32 * 8]);
    uint4 r1 = *reinterpret_cast<const uint4*>(&h[(size_t)s1 * HDIM + l32 * 8]);
    add8(acc, r0);
    add8(acc, r1);
  }
  for (; p < end; p += 2) {      // tail: 1..3 edges, pair-guarded
    int e = p + half;
    if (e < end) {
      int s = csr[e];
      uint4 r = *reinterpret_cast<const uint4*>(&h[(size_t)s * HDIM + l32 * 8]);
      add8(acc, r);
    }
  }
#pragma unroll
  for (int k = 0; k < 8; ++k) acc[k] += __shfl_xor(acc[k], 32);
  if (half == 0) {
    float iv = inv_deg[node];
    uint4 o;
    o.x = (unsigned)f2bf(acc[0] * iv) | ((unsigned)f2bf(acc[1] * iv) << 16);
    o.y = (unsigned)f2bf(acc[2] * iv) | ((unsigned)f2bf(acc[3] * iv) << 16);
    o.z = (unsigned)f2bf(acc[4] * iv) | ((unsigned)f2bf(acc[5] * iv) << 16);
    o.w = (unsigned)f2bf(acc[6] * iv) | ((unsigned)f2bf(acc[7] * iv) << 16);
    *reinterpret_cast<uint4*>(&mean[(size_t)node * HDIM + l32 * 8]) = o;
  }
}

// ---------------- output store helpers ----------------
__device__ __forceinline__ void store1(float* p, float v) { *p = v; }
__device__ __forceinline__ void store1(bf16_t* p, float v) { *p = f2bf(v); }

// ---------------- bf16 MFMA GEMM, fused bias + BN + ReLU ----------------
// C[M,OUT] = act( A0 @ W0^T (+ A1 @ W1^T) + bias ), W row-major [OUT,K] bf16.
// 128x128 block tile, BK=32, 4 waves (2x2), 4x4 fragments of 16x16x32 per wave.
// LDS row stride 40 bf16 (80B): frag ds_read_b128 conflict-free (G4 arithmetic).
#define LDSK 40

template <typename TOUT>
__global__ __launch_bounds__(256)
void gemm_mfma(const bf16_t* __restrict__ A0, const bf16_t* __restrict__ W0,
               const bf16_t* __restrict__ A1, const bf16_t* __restrict__ W1,
               const float* __restrict__ bias, const float* __restrict__ bn,
               TOUT* __restrict__ C, int M, int K, int OUT, int dual) {
  __shared__ bf16_t lds[2][(128 + 128) * LDSK];
  const int tid = threadIdx.x;
  const int lane = tid & 63, wid = tid >> 6;
  const int wm = wid >> 1, wn = wid & 1;
  const int row0 = blockIdx.x * 128, col0 = blockIdx.y * 128;
  const int l15 = lane & 15, l4 = lane >> 4;

  const int srow = tid >> 1;        // staging row 0..127
  const int sk = (tid & 1) * 16;    // staging k-offset (bf16) within BK=32

  const int nk = K / 32;
  const int nsteps = dual ? nk * 2 : nk;

  f32x4 acc[4][4] = {};
  uint4 va0, va1, vb0, vb1;

  auto stage_load = [&](int s) {
    const bf16_t* A = (s < nk) ? A0 : A1;
    const bf16_t* W = (s < nk) ? W0 : W1;
    int kk = ((s < nk) ? s : s - nk) * 32 + sk;
    uint4 z; z.x = z.y = z.z = z.w = 0u;
    va0 = z; va1 = z; vb0 = z; vb1 = z;
    int ar = row0 + srow;
    if (ar < M) {
      const uint4* p = reinterpret_cast<const uint4*>(&A[(size_t)ar * K + kk]);
      va0 = p[0]; va1 = p[1];
    }
    int br = col0 + srow;
    if (br < OUT) {
      const uint4* p = reinterpret_cast<const uint4*>(&W[(size_t)br * K + kk]);
      vb0 = p[0]; vb1 = p[1];
    }
  };
  auto stage_write = [&](int b) {
    uint4* la = reinterpret_cast<uint4*>(&lds[b][srow * LDSK + sk]);
    la[0] = va0; la[1] = va1;
    uint4* lb = reinterpret_cast<uint4*>(&lds[b][(128 + srow) * LDSK + sk]);
    lb[0] = vb0; lb[1] = vb1;
  };

  stage_load(0);
  stage_write(0);
  __syncthreads();
  int cur = 0;
  for (int s = 0; s < nsteps; ++s) {
    if (s + 1 < nsteps) stage_load(s + 1);   // global loads overlap MFMA below
    const bf16_t* pa = &lds[cur][(wm * 64 + l15) * LDSK + l4 * 8];
    const bf16_t* pb = &lds[cur][(128 + wn * 64 + l15) * LDSK + l4 * 8];
    bf16x8 a[4], b[4];
#pragma unroll
    for (int i = 0; i < 4; ++i) a[i] = *reinterpret_cast<const bf16x8*>(&pa[i * 16 * LDSK]);
#pragma unroll
    for (int j = 0; j < 4; ++j) b[j] = *reinterpret_cast<const bf16x8*>(&pb[j * 16 * LDSK]);
#pragma unroll
    for (int i = 0; i < 4; ++i)
#pragma unroll
      for (int j = 0; j < 4; ++j)
        acc[i][j] = __builtin_amdgcn_mfma_f32_16x16x32_bf16(a[i], b[j], acc[i][j], 0, 0, 0);
    if (s + 1 < nsteps) {
      stage_write(cur ^ 1);
      __syncthreads();
      cur ^= 1;
    }
  }

  // epilogue: C/D frag mapping col=lane&15, row=(lane>>4)*4+reg  [m89]
#pragma unroll
  for (int j = 0; j < 4; ++j) {
    int col = col0 + wn * 64 + j * 16 + l15;
    if (col >= OUT) continue;
    float bs = bias ? bias[col] : 0.f;
    float scale = 1.f, shift = bs;
    bool has_bn = (bn != nullptr);
    if (has_bn) {
      float g = bn[col], bb = bn[256 + col], mm = bn[512 + col], vv = bn[768 + col];
      float is = g * rsqrtf(vv + BN_EPS);
      scale = is; shift = (bs - mm) * is + bb;
    }
#pragma unroll
    for (int i = 0; i < 4; ++i) {
#pragma unroll
      for (int r = 0; r < 4; ++r) {
        int row = row0 + wm * 64 + i * 16 + l4 * 4 + r;
        if (row >= M) continue;
        float v = acc[i][j][r];
        v = has_bn ? fmaxf(v * scale + shift, 0.f) : (v + bs);
        store1(&C[(size_t)row * OUT + col], v);
      }
    }
  }
}

// ---------------- row log-softmax (C=40) ----------------
__global__ __launch_bounds__(256)
void k_logsoftmax(const float* __restrict__ logits, float* __restrict__ out, int M) {
  int row = blockIdx.x * 4 + (threadIdx.x >> 6);
  if (row >= M) return;
  int lane = threadIdx.x & 63;
  float v = (lane < C_OUT) ? logits[(size_t)row * C_OUT + lane] : -1e30f;
  float m = v;
#pragma unroll
  for (int o = 32; o; o >>= 1) m = fmaxf(m, __shfl_xor(m, o));
  float e = (lane < C_OUT) ? expf(v - m) : 0.f;
  float s = e;
#pragma unroll
  for (int o = 32; o; o >>= 1) s += __shfl_xor(s, o);
  if (lane < C_OUT) out[(size_t)row * C_OUT + lane] = v - m - logf(s);
}

// ---------------- host launch ----------------
extern "C" void kernel_launch(void* const* d_in, const int* in_sizes, int n_in,
                              void* d_out, int out_size, void* d_ws, size_t ws_size,
                              hipStream_t stream) {
  const float* x       = (const float*)d_in[0];
  const int*   ei      = (const int*)d_in[1];   // [2, E] int32
  const float* pre_w   = (const float*)d_in[2];
  const float* pre_b   = (const float*)d_in[3];
  const float* bn      = (const float*)d_in[4]; // [5,4,256]
  const float* lin_l_w = (const float*)d_in[5];
  const float* lin_l_b = (const float*)d_in[6];
  const float* lin_r_w = (const float*)d_in[7];
  const float* post1_w = (const float*)d_in[8];
  const float* post1_b = (const float*)d_in[9];
  const float* post2_w = (const float*)d_in[10];
  const float* post2_b = (const float*)d_in[11];
  float* out = (float*)d_out;

  const int* src = ei;
  const int* dstv = ei + N_EDGES;

  char* base = (char*)d_ws;
  size_t off = 0;
  auto alloc = [&](size_t bytes) -> void* {
    void* p = base + off;
    off = (off + bytes + 255) & ~(size_t)255;
    return p;
  };
  bf16_t* hA = (bf16_t*)alloc((size_t)N_NODES * HDIM * 2);
  bf16_t* hB = (bf16_t*)alloc((size_t)N_NODES * HDIM * 2);  // also x_bf16 pre-GEMM, f32 logits post
  bf16_t* hC = (bf16_t*)alloc((size_t)N_NODES * HDIM * 2);
  int* row_ptr = (int*)alloc((size_t)(N_NODES + 1) * 4);
  int* cnt     = (int*)alloc((size_t)N_NODES * 4);
  int* cursor  = (int*)alloc((size_t)N_NODES * 4);
  int* csr     = (int*)alloc((size_t)N_EDGES * 4);
  float* inv   = (float*)alloc((size_t)N_NODES * 4);
  int* blk_sum = (int*)alloc(128 * 4);
  int* blk_off = (int*)alloc(128 * 4);
  bf16_t* w_pre = (bf16_t*)alloc((size_t)HDIM * F_INDIM * 2);
  bf16_t* w_ll  = (bf16_t*)alloc((size_t)3 * HDIM * HDIM * 2);
  bf16_t* w_lr  = (bf16_t*)alloc((size_t)3 * HDIM * HDIM * 2);
  bf16_t* w_p1  = (bf16_t*)alloc((size_t)HDIM * HDIM * 2);
  bf16_t* w_p2  = (bf16_t*)alloc((size_t)C_OUT * HDIM * 2);
  (void)n_in; (void)in_sizes; (void)out_size;
  if (off > ws_size) return;  // visible failure (zeros), no fault

  bf16_t* x_bf = hB;

  // weight/input conversions
  {
    int n;
    n = N_NODES * F_INDIM;
    k_cvt<<<(n / 4 + 255) / 256, 256, 0, stream>>>(x, x_bf, n);
    n = HDIM * F_INDIM;
    k_cvt<<<(n / 4 + 255) / 256, 256, 0, stream>>>(pre_w, w_pre, n);
    n = 3 * HDIM * HDIM;
    k_cvt<<<(n / 4 + 255) / 256, 256, 0, stream>>>(lin_l_w, w_ll, n);
    k_cvt<<<(n / 4 + 255) / 256, 256, 0, stream>>>(lin_r_w, w_lr, n);
    n = HDIM * HDIM;
    k_cvt<<<(n / 4 + 255) / 256, 256, 0, stream>>>(post1_w, w_p1, n);
    n = C_OUT * HDIM;
    k_cvt<<<(n / 4 + 255) / 256, 256, 0, stream>>>(post2_w, w_p2, n);
  }

  // CSR build
  hipMemsetAsync(cnt, 0, (size_t)N_NODES * 4, stream);
  hipMemsetAsync(cursor, 0, (size_t)N_NODES * 4, stream);
  k_hist<<<2048, 256, 0, stream>>>(dstv, cnt, N_EDGES);
  int nb = (N_NODES + 1023) / 1024;  // 98
  k_scan_local<<<nb, 1024, 0, stream>>>(cnt, row_ptr, blk_sum, N_NODES);
  k_scan_blk<<<1, 128, 0, stream>>>(blk_sum, blk_off, nb);
  k_scan_add<<<(N_NODES + 255) / 256, 256, 0, stream>>>(row_ptr, blk_off, N_NODES);
  k_fill<<<2048, 256, 0, stream>>>(src, dstv, row_ptr, cursor, csr, N_EDGES);
  k_inv<<<(N_NODES + 255) / 256, 256, 0, stream>>>(cnt, inv, N_NODES);

  dim3 gH((N_NODES + 127) / 128, 2);   // OUT=256
  // pre: h = relu(bn0(x @ pre_w^T + pre_b))
  gemm_mfma<bf16_t><<<gH, 256, 0, stream>>>(
      x_bf, w_pre, nullptr, nullptr, pre_b, bn, hA, N_NODES, F_INDIM, HDIM, 0);

  bf16_t* hcur = hA;
  bf16_t* hnext = hC;
  for (int i = 0; i < 3; ++i) {
    k_aggregate<<<N_NODES / 4, 256, 0, stream>>>(hcur, row_ptr, csr, inv, hB);
    gemm_mfma<bf16_t><<<gH, 256, 0, stream>>>(
        hB, w_ll + (size_t)i * HDIM * HDIM,
        hcur, w_lr + (size_t)i * HDIM * HDIM,
        lin_l_b + (size_t)i * HDIM,
        bn + (size_t)(i + 1) * 4 * HDIM,
        hnext, N_NODES, HDIM, HDIM, 1);
    bf16_t* t = hcur; hcur = hnext; hnext = t;
  }
  // post1
  gemm_mfma<bf16_t><<<gH, 256, 0, stream>>>(
      hcur, w_p1, nullptr, nullptr, post1_b,
      bn + (size_t)4 * 4 * HDIM, hnext, N_NODES, HDIM, HDIM, 0);
  // post2 -> f32 logits (no bn); hB is free now
  float* logits = (float*)hB;
  dim3 gC((N_NODES + 127) / 128, 1);
  gemm_mfma<float><<<gC, 256, 0, stream>>>(
      hnext, w_p2, nullptr, nullptr, post2_b,
      nullptr, logits, N_NODES, HDIM, C_OUT, 0);
  k_logsoftmax<<<(N_NODES + 3) / 4, 256, 0, stream>>>(logits, out, N_NODES);
}

// Round 7
// 878.911 us; speedup vs baseline: 3.7729x; 1.0058x over previous
//
#include <hip/hip_runtime.h>
#include <cstdint>
#include <cstddef>

#define N_NODES 100000
#define N_EDGES 1600000
#define F_INDIM 128
#define HDIM 256
#define C_OUT 40
#define BN_EPS 1e-5f

typedef unsigned short bf16_t;
typedef __attribute__((ext_vector_type(8))) short bf16x8;
typedef __attribute__((ext_vector_type(4))) float f32x4;

__device__ __forceinline__ float bf2f(unsigned int u) {
  return __uint_as_float(u << 16);
}
__device__ __forceinline__ bf16_t f2bf(float f) {
  unsigned int x = __float_as_uint(f);
  return (bf16_t)((x + 0x7fffu + ((x >> 16) & 1u)) >> 16);
}

// ---------------- f32 -> bf16 conversion (n % 4 == 0) ----------------
__global__ void k_cvt(const float* __restrict__ s, bf16_t* __restrict__ d, int n) {
  int i = (blockIdx.x * blockDim.x + threadIdx.x) * 4;
  if (i >= n) return;
  float4 v = *reinterpret_cast<const float4*>(&s[i]);
  uint2 o;
  o.x = (unsigned)f2bf(v.x) | ((unsigned)f2bf(v.y) << 16);
  o.y = (unsigned)f2bf(v.z) | ((unsigned)f2bf(v.w) << 16);
  *reinterpret_cast<uint2*>(&d[i]) = o;
}

// ---------------- CSR build ----------------
__global__ void k_hist(const int* __restrict__ dst, int* __restrict__ cnt, int E) {
  for (int e = blockIdx.x * blockDim.x + threadIdx.x; e < E; e += gridDim.x * blockDim.x)
    atomicAdd(&cnt[dst[e]], 1);
}

__global__ __launch_bounds__(1024)
void k_scan_local(const int* __restrict__ cnt, int* __restrict__ row_ptr,
                  int* __restrict__ blk_sum, int n) {
  __shared__ int buf[1024];
  int tid = threadIdx.x;
  int i = blockIdx.x * 1024 + tid;
  int v = (i < n) ? cnt[i] : 0;
  buf[tid] = v;
  __syncthreads();
  for (int off = 1; off < 1024; off <<= 1) {
    int t = (tid >= off) ? buf[tid - off] : 0;
    __syncthreads();
    buf[tid] += t;
    __syncthreads();
  }
  if (i < n) row_ptr[i] = buf[tid] - v;       // block-local exclusive
  if (tid == 1023) blk_sum[blockIdx.x] = buf[1023];
}

__global__ __launch_bounds__(128)
void k_scan_blk(const int* __restrict__ blk_sum, int* __restrict__ blk_off, int nb) {
  __shared__ int buf[128];
  int tid = threadIdx.x;
  int v = (tid < nb) ? blk_sum[tid] : 0;
  buf[tid] = v;
  __syncthreads();
  for (int off = 1; off < 128; off <<= 1) {
    int t = (tid >= off) ? buf[tid - off] : 0;
    __syncthreads();
    buf[tid] += t;
    __syncthreads();
  }
  if (tid < nb) blk_off[tid] = buf[tid] - v;  // exclusive
}

__global__ void k_scan_add(int* __restrict__ row_ptr, const int* __restrict__ blk_off, int n) {
  int i = blockIdx.x * blockDim.x + threadIdx.x;
  if (i < n) row_ptr[i] += blk_off[i >> 10];
  if (i == 0) row_ptr[n] = N_EDGES;
}

__global__ void k_fill(const int* __restrict__ src, const int* __restrict__ dst,
                       const int* __restrict__ row_ptr, int* __restrict__ cursor,
                       int* __restrict__ csr, int E) {
  for (int e = blockIdx.x * blockDim.x + threadIdx.x; e < E; e += gridDim.x * blockDim.x) {
    int d = dst[e];
    int p = atomicAdd(&cursor[d], 1);
    csr[row_ptr[d] + p] = src[e];
  }
}

__global__ void k_inv(const int* __restrict__ cnt, float* __restrict__ inv, int n) {
  int i = blockIdx.x * blockDim.x + threadIdx.x;
  if (i < n) inv[i] = 1.0f / (float)(cnt[i] > 0 ? cnt[i] : 1);
}

// ---------------- mean aggregation ----------------
// One wave per node. Half-wave (32 lanes x 16B) covers one 512B feature row,
// so a wave processes 2 edges per step. 8-edge unroll keeps 4 independent
// row-loads (+4 index loads) in flight per lane; 4-edge block then pair loop
// shorten the dependent tail. Cross-half combine via shfl_xor(32).
__device__ __forceinline__ void add8(float* acc, uint4 r) {
  acc[0] += bf2f(r.x & 0xffffu); acc[1] += bf2f(r.x >> 16);
  acc[2] += bf2f(r.y & 0xffffu); acc[3] += bf2f(r.y >> 16);
  acc[4] += bf2f(r.z & 0xffffu); acc[5] += bf2f(r.z >> 16);
  acc[6] += bf2f(r.w & 0xffffu); acc[7] += bf2f(r.w >> 16);
}

__global__ __launch_bounds__(256)
void k_aggregate(const bf16_t* __restrict__ h, const int* __restrict__ row_ptr,
                 const int* __restrict__ csr, const float* __restrict__ inv_deg,
                 bf16_t* __restrict__ mean) {
  int w = threadIdx.x >> 6, lane = threadIdx.x & 63;
  int node = blockIdx.x * 4 + w;
  if (node >= N_NODES) return;
  int beg = row_ptr[node], end = row_ptr[node + 1];
  int half = lane >> 5;         // 0 or 1: which edge of the pair
  int l32 = lane & 31;          // 16B column block within the row
  float acc[8] = {};
  int deg = end - beg;
  int p = beg;
  int p8 = beg + (deg & ~7);
  for (; p < p8; p += 8) {       // 8 edges per iteration, 4 row loads/lane in flight
    int s0 = csr[p + half];
    int s1 = csr[p + 2 + half];
    int s2 = csr[p + 4 + half];
    int s3 = csr[p + 6 + half];
    uint4 r0 = *reinterpret_cast<const uint4*>(&h[(size_t)s0 * HDIM + l32 * 8]);
    uint4 r1 = *reinterpret_cast<const uint4*>(&h[(size_t)s1 * HDIM + l32 * 8]);
    uint4 r2 = *reinterpret_cast<const uint4*>(&h[(size_t)s2 * HDIM + l32 * 8]);
    uint4 r3 = *reinterpret_cast<const uint4*>(&h[(size_t)s3 * HDIM + l32 * 8]);
    add8(acc, r0);
    add8(acc, r1);
    add8(acc, r2);
    add8(acc, r3);
  }
  if (end - p >= 4) {            // 4-edge block: 2 row loads in flight
    int s0 = csr[p + half];
    int s1 = csr[p + 2 + half];
    uint4 r0 = *reinterpret_cast<const uint4*>(&h[(size_t)s0 * HDIM + l32 * 8]);
    uint4 r1 = *reinterpret_cast<const uint4*>(&h[(size_t)s1 * HDIM + l32 * 8]);
    add8(acc, r0);
    add8(acc, r1);
    p += 4;
  }
  for (; p < end; p += 2) {      // tail: <=3 edges, pair-guarded
    int e = p + half;
    if (e < end) {
      int s = csr[e];
      uint4 r = *reinterpret_cast<const uint4*>(&h[(size_t)s * HDIM + l32 * 8]);
      add8(acc, r);
    }
  }
#pragma unroll
  for (int k = 0; k < 8; ++k) acc[k] += __shfl_xor(acc[k], 32);
  if (half == 0) {
    float iv = inv_deg[node];
    uint4 o;
    o.x = (unsigned)f2bf(acc[0] * iv) | ((unsigned)f2bf(acc[1] * iv) << 16);
    o.y = (unsigned)f2bf(acc[2] * iv) | ((unsigned)f2bf(acc[3] * iv) << 16);
    o.z = (unsigned)f2bf(acc[4] * iv) | ((unsigned)f2bf(acc[5] * iv) << 16);
    o.w = (unsigned)f2bf(acc[6] * iv) | ((unsigned)f2bf(acc[7] * iv) << 16);
    *reinterpret_cast<uint4*>(&mean[(size_t)node * HDIM + l32 * 8]) = o;
  }
}

// ---------------- output store helpers ----------------
__device__ __forceinline__ void store1(float* p, float v) { *p = v; }
__device__ __forceinline__ void store1(bf16_t* p, float v) { *p = f2bf(v); }

// ---------------- bf16 MFMA GEMM, fused bias + BN + ReLU ----------------
// C[M,OUT] = act( A0 @ W0^T (+ A1 @ W1^T) + bias ), W row-major [OUT,K] bf16.
// 128x128 block tile, BK=32, 4 waves (2x2), 4x4 fragments of 16x16x32 per wave.
// LDS row stride 40 bf16 (80B): frag ds_read_b128 conflict-free (G4 arithmetic).
#define LDSK 40

template <typename TOUT>
__global__ __launch_bounds__(256)
void gemm_mfma(const bf16_t* __restrict__ A0, const bf16_t* __restrict__ W0,
               const bf16_t* __restrict__ A1, const bf16_t* __restrict__ W1,
               const float* __restrict__ bias, const float* __restrict__ bn,
               TOUT* __restrict__ C, int M, int K, int OUT, int dual) {
  __shared__ bf16_t lds[2][(128 + 128) * LDSK];
  const int tid = threadIdx.x;
  const int lane = tid & 63, wid = tid >> 6;
  const int wm = wid >> 1, wn = wid & 1;
  const int row0 = blockIdx.x * 128, col0 = blockIdx.y * 128;
  const int l15 = lane & 15, l4 = lane >> 4;

  const int srow = tid >> 1;        // staging row 0..127
  const int sk = (tid & 1) * 16;    // staging k-offset (bf16) within BK=32

  const int nk = K / 32;
  const int nsteps = dual ? nk * 2 : nk;

  f32x4 acc[4][4] = {};
  uint4 va0, va1, vb0, vb1;

  auto stage_load = [&](int s) {
    const bf16_t* A = (s < nk) ? A0 : A1;
    const bf16_t* W = (s < nk) ? W0 : W1;
    int kk = ((s < nk) ? s : s - nk) * 32 + sk;
    uint4 z; z.x = z.y = z.z = z.w = 0u;
    va0 = z; va1 = z; vb0 = z; vb1 = z;
    int ar = row0 + srow;
    if (ar < M) {
      const uint4* p = reinterpret_cast<const uint4*>(&A[(size_t)ar * K + kk]);
      va0 = p[0]; va1 = p[1];
    }
    int br = col0 + srow;
    if (br < OUT) {
      const uint4* p = reinterpret_cast<const uint4*>(&W[(size_t)br * K + kk]);
      vb0 = p[0]; vb1 = p[1];
    }
  };
  auto stage_write = [&](int b) {
    uint4* la = reinterpret_cast<uint4*>(&lds[b][srow * LDSK + sk]);
    la[0] = va0; la[1] = va1;
    uint4* lb = reinterpret_cast<uint4*>(&lds[b][(128 + srow) * LDSK + sk]);
    lb[0] = vb0; lb[1] = vb1;
  };

  stage_load(0);
  stage_write(0);
  __syncthreads();
  int cur = 0;
  for (int s = 0; s < nsteps; ++s) {
    if (s + 1 < nsteps) stage_load(s + 1);   // global loads overlap MFMA below
    const bf16_t* pa = &lds[cur][(wm * 64 + l15) * LDSK + l4 * 8];
    const bf16_t* pb = &lds[cur][(128 + wn * 64 + l15) * LDSK + l4 * 8];
    bf16x8 a[4], b[4];
#pragma unroll
    for (int i = 0; i < 4; ++i) a[i] = *reinterpret_cast<const bf16x8*>(&pa[i * 16 * LDSK]);
#pragma unroll
    for (int j = 0; j < 4; ++j) b[j] = *reinterpret_cast<const bf16x8*>(&pb[j * 16 * LDSK]);
#pragma unroll
    for (int i = 0; i < 4; ++i)
#pragma unroll
      for (int j = 0; j < 4; ++j)
        acc[i][j] = __builtin_amdgcn_mfma_f32_16x16x32_bf16(a[i], b[j], acc[i][j], 0, 0, 0);
    if (s + 1 < nsteps) {
      stage_write(cur ^ 1);
      __syncthreads();
      cur ^= 1;
    }
  }

  // epilogue: C/D frag mapping col=lane&15, row=(lane>>4)*4+reg  [m89]
#pragma unroll
  for (int j = 0; j < 4; ++j) {
    int col = col0 + wn * 64 + j * 16 + l15;
    if (col >= OUT) continue;
    float bs = bias ? bias[col] : 0.f;
    float scale = 1.f, shift = bs;
    bool has_bn = (bn != nullptr);
    if (has_bn) {
      float g = bn[col], bb = bn[256 + col], mm = bn[512 + col], vv = bn[768 + col];
      float is = g * rsqrtf(vv + BN_EPS);
      scale = is; shift = (bs - mm) * is + bb;
    }
#pragma unroll
    for (int i = 0; i < 4; ++i) {
#pragma unroll
      for (int r = 0; r < 4; ++r) {
        int row = row0 + wm * 64 + i * 16 + l4 * 4 + r;
        if (row >= M) continue;
        float v = acc[i][j][r];
        v = has_bn ? fmaxf(v * scale + shift, 0.f) : (v + bs);
        store1(&C[(size_t)row * OUT + col], v);
      }
    }
  }
}

// ---------------- row log-softmax (C=40) ----------------
__global__ __launch_bounds__(256)
void k_logsoftmax(const float* __restrict__ logits, float* __restrict__ out, int M) {
  int row = blockIdx.x * 4 + (threadIdx.x >> 6);
  if (row >= M) return;
  int lane = threadIdx.x & 63;
  float v = (lane < C_OUT) ? logits[(size_t)row * C_OUT + lane] : -1e30f;
  float m = v;
#pragma unroll
  for (int o = 32; o; o >>= 1) m = fmaxf(m, __shfl_xor(m, o));
  float e = (lane < C_OUT) ? expf(v - m) : 0.f;
  float s = e;
#pragma unroll
  for (int o = 32; o; o >>= 1) s += __shfl_xor(s, o);
  if (lane < C_OUT) out[(size_t)row * C_OUT + lane] = v - m - logf(s);
}

// ---------------- host launch ----------------
extern "C" void kernel_launch(void* const* d_in, const int* in_sizes, int n_in,
                              void* d_out, int out_size, void* d_ws, size_t ws_size,
                              hipStream_t stream) {
  const float* x       = (const float*)d_in[0];
  const int*   ei      = (const int*)d_in[1];   // [2, E] int32
  const float* pre_w   = (const float*)d_in[2];
  const float* pre_b   = (const float*)d_in[3];
  const float* bn      = (const float*)d_in[4]; // [5,4,256]
  const float* lin_l_w = (const float*)d_in[5];
  const float* lin_l_b = (const float*)d_in[6];
  const float* lin_r_w = (const float*)d_in[7];
  const float* post1_w = (const float*)d_in[8];
  const float* post1_b = (const float*)d_in[9];
  const float* post2_w = (const float*)d_in[10];
  const float* post2_b = (const float*)d_in[11];
  float* out = (float*)d_out;

  const int* src = ei;
  const int* dstv = ei + N_EDGES;

  char* base = (char*)d_ws;
  size_t off = 0;
  auto alloc = [&](size_t bytes) -> void* {
    void* p = base + off;
    off = (off + bytes + 255) & ~(size_t)255;
    return p;
  };
  bf16_t* hA = (bf16_t*)alloc((size_t)N_NODES * HDIM * 2);
  bf16_t* hB = (bf16_t*)alloc((size_t)N_NODES * HDIM * 2);  // also x_bf16 pre-GEMM, f32 logits post
  bf16_t* hC = (bf16_t*)alloc((size_t)N_NODES * HDIM * 2);
  int* row_ptr = (int*)alloc((size_t)(N_NODES + 1) * 4);
  int* cnt     = (int*)alloc((size_t)N_NODES * 4);
  int* cursor  = (int*)alloc((size_t)N_NODES * 4);
  int* csr     = (int*)alloc((size_t)N_EDGES * 4);
  float* inv   = (float*)alloc((size_t)N_NODES * 4);
  int* blk_sum = (int*)alloc(128 * 4);
  int* blk_off = (int*)alloc(128 * 4);
  bf16_t* w_pre = (bf16_t*)alloc((size_t)HDIM * F_INDIM * 2);
  bf16_t* w_ll  = (bf16_t*)alloc((size_t)3 * HDIM * HDIM * 2);
  bf16_t* w_lr  = (bf16_t*)alloc((size_t)3 * HDIM * HDIM * 2);
  bf16_t* w_p1  = (bf16_t*)alloc((size_t)HDIM * HDIM * 2);
  bf16_t* w_p2  = (bf16_t*)alloc((size_t)C_OUT * HDIM * 2);
  (void)n_in; (void)in_sizes; (void)out_size;
  if (off > ws_size) return;  // visible failure (zeros), no fault

  bf16_t* x_bf = hB;

  // weight/input conversions
  {
    int n;
    n = N_NODES * F_INDIM;
    k_cvt<<<(n / 4 + 255) / 256, 256, 0, stream>>>(x, x_bf, n);
    n = HDIM * F_INDIM;
    k_cvt<<<(n / 4 + 255) / 256, 256, 0, stream>>>(pre_w, w_pre, n);
    n = 3 * HDIM * HDIM;
    k_cvt<<<(n / 4 + 255) / 256, 256, 0, stream>>>(lin_l_w, w_ll, n);
    k_cvt<<<(n / 4 + 255) / 256, 256, 0, stream>>>(lin_r_w, w_lr, n);
    n = HDIM * HDIM;
    k_cvt<<<(n / 4 + 255) / 256, 256, 0, stream>>>(post1_w, w_p1, n);
    n = C_OUT * HDIM;
    k_cvt<<<(n / 4 + 255) / 256, 256, 0, stream>>>(post2_w, w_p2, n);
  }

  // CSR build
  hipMemsetAsync(cnt, 0, (size_t)N_NODES * 4, stream);
  hipMemsetAsync(cursor, 0, (size_t)N_NODES * 4, stream);
  k_hist<<<2048, 256, 0, stream>>>(dstv, cnt, N_EDGES);
  int nb = (N_NODES + 1023) / 1024;  // 98
  k_scan_local<<<nb, 1024, 0, stream>>>(cnt, row_ptr, blk_sum, N_NODES);
  k_scan_blk<<<1, 128, 0, stream>>>(blk_sum, blk_off, nb);
  k_scan_add<<<(N_NODES + 255) / 256, 256, 0, stream>>>(row_ptr, blk_off, N_NODES);
  k_fill<<<2048, 256, 0, stream>>>(src, dstv, row_ptr, cursor, csr, N_EDGES);
  k_inv<<<(N_NODES + 255) / 256, 256, 0, stream>>>(cnt, inv, N_NODES);

  dim3 gH((N_NODES + 127) / 128, 2);   // OUT=256
  // pre: h = relu(bn0(x @ pre_w^T + pre_b))
  gemm_mfma<bf16_t><<<gH, 256, 0, stream>>>(
      x_bf, w_pre, nullptr, nullptr, pre_b, bn, hA, N_NODES, F_INDIM, HDIM, 0);

  bf16_t* hcur = hA;
  bf16_t* hnext = hC;
  for (int i = 0; i < 3; ++i) {
    k_aggregate<<<N_NODES / 4, 256, 0, stream>>>(hcur, row_ptr, csr, inv, hB);
    gemm_mfma<bf16_t><<<gH, 256, 0, stream>>>(
        hB, w_ll + (size_t)i * HDIM * HDIM,
        hcur, w_lr + (size_t)i * HDIM * HDIM,
        lin_l_b + (size_t)i * HDIM,
        bn + (size_t)(i + 1) * 4 * HDIM,
        hnext, N_NODES, HDIM, HDIM, 1);
    bf16_t* t = hcur; hcur = hnext; hnext = t;
  }
  // post1
  gemm_mfma<bf16_t><<<gH, 256, 0, stream>>>(
      hcur, w_p1, nullptr, nullptr, post1_b,
      bn + (size_t)4 * 4 * HDIM, hnext, N_NODES, HDIM, HDIM, 0);
  // post2 -> f32 logits (no bn); hB is free now
  float* logits = (float*)hB;
  dim3 gC((N_NODES + 127) / 128, 1);
  gemm_mfma<float><<<gC, 256, 0, stream>>>(
      hnext, w_p2, nullptr, nullptr, post2_b,
      nullptr, logits, N_NODES, HDIM, C_OUT, 0);
  k_logsoftmax<<<(N_NODES + 3) / 4, 256, 0, stream>>>(logits, out, N_NODES);
}

// Round 8
// 813.353 us; speedup vs baseline: 4.0770x; 1.0806x over previous
//
#include <hip/hip_runtime.h>
#include <cstdint>
#include <cstddef>

#define N_NODES 100000
#define N_EDGES 1600000
#define F_INDIM 128
#define HDIM 256
#define C_OUT 40
#define BN_EPS 1e-5f

typedef unsigned short bf16_t;
typedef __attribute__((ext_vector_type(8))) short bf16x8;
typedef __attribute__((ext_vector_type(4))) float f32x4;

__device__ __forceinline__ float bf2f(unsigned int u) {
  return __uint_as_float(u << 16);
}
__device__ __forceinline__ bf16_t f2bf(float f) {
  unsigned int x = __float_as_uint(f);
  return (bf16_t)((x + 0x7fffu + ((x >> 16) & 1u)) >> 16);
}

// ---------------- f32 -> bf16 conversion (n % 4 == 0) ----------------
__global__ void k_cvt(const float* __restrict__ s, bf16_t* __restrict__ d, int n) {
  int i = (blockIdx.x * blockDim.x + threadIdx.x) * 4;
  if (i >= n) return;
  float4 v = *reinterpret_cast<const float4*>(&s[i]);
  uint2 o;
  o.x = (unsigned)f2bf(v.x) | ((unsigned)f2bf(v.y) << 16);
  o.y = (unsigned)f2bf(v.z) | ((unsigned)f2bf(v.w) << 16);
  *reinterpret_cast<uint2*>(&d[i]) = o;
}

// ---------------- CSR build (merged hist+rank, atomic-free placement) -------
// Pass 1: rank[e] = atomicAdd(&cursor[dst[e]],1)  (cursor doubles as histogram)
// Scan  : row_ptr = exclusive_scan(cursor)
// Pass 2: csr[row_ptr[dst[e]] + rank[e]] = src[e]  (no atomics)
__global__ void k_rank(const int* __restrict__ dst, int* __restrict__ cursor,
                       int* __restrict__ rank, int E) {
  for (int e = blockIdx.x * blockDim.x + threadIdx.x; e < E; e += gridDim.x * blockDim.x)
    rank[e] = atomicAdd(&cursor[dst[e]], 1);
}

__global__ __launch_bounds__(1024)
void k_scan_local(const int* __restrict__ cnt, int* __restrict__ row_ptr,
                  int* __restrict__ blk_sum, int n) {
  __shared__ int buf[1024];
  int tid = threadIdx.x;
  int i = blockIdx.x * 1024 + tid;
  int v = (i < n) ? cnt[i] : 0;
  buf[tid] = v;
  __syncthreads();
  for (int off = 1; off < 1024; off <<= 1) {
    int t = (tid >= off) ? buf[tid - off] : 0;
    __syncthreads();
    buf[tid] += t;
    __syncthreads();
  }
  if (i < n) row_ptr[i] = buf[tid] - v;       // block-local exclusive
  if (tid == 1023) blk_sum[blockIdx.x] = buf[1023];
}

__global__ __launch_bounds__(128)
void k_scan_blk(const int* __restrict__ blk_sum, int* __restrict__ blk_off, int nb) {
  __shared__ int buf[128];
  int tid = threadIdx.x;
  int v = (tid < nb) ? blk_sum[tid] : 0;
  buf[tid] = v;
  __syncthreads();
  for (int off = 1; off < 128; off <<= 1) {
    int t = (tid >= off) ? buf[tid - off] : 0;
    __syncthreads();
    buf[tid] += t;
    __syncthreads();
  }
  if (tid < nb) blk_off[tid] = buf[tid] - v;  // exclusive
}

__global__ void k_scan_add(int* __restrict__ row_ptr, const int* __restrict__ blk_off, int n) {
  int i = blockIdx.x * blockDim.x + threadIdx.x;
  if (i < n) row_ptr[i] += blk_off[i >> 10];
  if (i == 0) row_ptr[n] = N_EDGES;
}

__global__ void k_place(const int* __restrict__ src, const int* __restrict__ dst,
                        const int* __restrict__ rank, const int* __restrict__ row_ptr,
                        int* __restrict__ csr, int E) {
  for (int e = blockIdx.x * blockDim.x + threadIdx.x; e < E; e += gridDim.x * blockDim.x)
    csr[row_ptr[dst[e]] + rank[e]] = src[e];
}

__global__ void k_inv(const int* __restrict__ cnt, float* __restrict__ inv, int n) {
  int i = blockIdx.x * blockDim.x + threadIdx.x;
  if (i < n) inv[i] = 1.0f / (float)(cnt[i] > 0 ? cnt[i] : 1);
}

// ---------------- mean aggregation ----------------
// One wave per node. Half-wave (32 lanes x 16B) covers one 512B feature row,
// so a wave processes 2 edges per step. 8-edge unroll keeps 4 independent
// row-loads (+4 index loads) in flight per lane; 4-edge block then pair loop
// shorten the dependent tail. Cross-half combine via shfl_xor(32).
__device__ __forceinline__ void add8(float* acc, uint4 r) {
  acc[0] += bf2f(r.x & 0xffffu); acc[1] += bf2f(r.x >> 16);
  acc[2] += bf2f(r.y & 0xffffu); acc[3] += bf2f(r.y >> 16);
  acc[4] += bf2f(r.z & 0xffffu); acc[5] += bf2f(r.z >> 16);
  acc[6] += bf2f(r.w & 0xffffu); acc[7] += bf2f(r.w >> 16);
}

__global__ __launch_bounds__(256)
void k_aggregate(const bf16_t* __restrict__ h, const int* __restrict__ row_ptr,
                 const int* __restrict__ csr, const float* __restrict__ inv_deg,
                 bf16_t* __restrict__ mean) {
  int w = threadIdx.x >> 6, lane = threadIdx.x & 63;
  int node = blockIdx.x * 4 + w;
  if (node >= N_NODES) return;
  int beg = row_ptr[node], end = row_ptr[node + 1];
  int half = lane >> 5;         // 0 or 1: which edge of the pair
  int l32 = lane & 31;          // 16B column block within the row
  float acc[8] = {};
  int deg = end - beg;
  int p = beg;
  int p8 = beg + (deg & ~7);
  for (; p < p8; p += 8) {       // 8 edges per iteration, 4 row loads/lane in flight
    int s0 = csr[p + half];
    int s1 = csr[p + 2 + half];
    int s2 = csr[p + 4 + half];
    int s3 = csr[p + 6 + half];
    uint4 r0 = *reinterpret_cast<const uint4*>(&h[(size_t)s0 * HDIM + l32 * 8]);
    uint4 r1 = *reinterpret_cast<const uint4*>(&h[(size_t)s1 * HDIM + l32 * 8]);
    uint4 r2 = *reinterpret_cast<const uint4*>(&h[(size_t)s2 * HDIM + l32 * 8]);
    uint4 r3 = *reinterpret_cast<const uint4*>(&h[(size_t)s3 * HDIM + l32 * 8]);
    add8(acc, r0);
    add8(acc, r1);
    add8(acc, r2);
    add8(acc, r3);
  }
  if (end - p >= 4) {            // 4-edge block: 2 row loads in flight
    int s0 = csr[p + half];
    int s1 = csr[p + 2 + half];
    uint4 r0 = *reinterpret_cast<const uint4*>(&h[(size_t)s0 * HDIM + l32 * 8]);
    uint4 r1 = *reinterpret_cast<const uint4*>(&h[(size_t)s1 * HDIM + l32 * 8]);
    add8(acc, r0);
    add8(acc, r1);
    p += 4;
  }
  for (; p < end; p += 2) {      // tail: <=3 edges, pair-guarded
    int e = p + half;
    if (e < end) {
      int s = csr[e];
      uint4 r = *reinterpret_cast<const uint4*>(&h[(size_t)s * HDIM + l32 * 8]);
      add8(acc, r);
    }
  }
#pragma unroll
  for (int k = 0; k < 8; ++k) acc[k] += __shfl_xor(acc[k], 32);
  if (half == 0) {
    float iv = inv_deg[node];
    uint4 o;
    o.x = (unsigned)f2bf(acc[0] * iv) | ((unsigned)f2bf(acc[1] * iv) << 16);
    o.y = (unsigned)f2bf(acc[2] * iv) | ((unsigned)f2bf(acc[3] * iv) << 16);
    o.z = (unsigned)f2bf(acc[4] * iv) | ((unsigned)f2bf(acc[5] * iv) << 16);
    o.w = (unsigned)f2bf(acc[6] * iv) | ((unsigned)f2bf(acc[7] * iv) << 16);
    *reinterpret_cast<uint4*>(&mean[(size_t)node * HDIM + l32 * 8]) = o;
  }
}

// ---------------- output store helpers ----------------
__device__ __forceinline__ void store1(float* p, float v) { *p = v; }
__device__ __forceinline__ void store1(bf16_t* p, float v) { *p = f2bf(v); }

// ---------------- bf16 MFMA GEMM, fused bias + BN + ReLU ----------------
// C[M,OUT] = act( A0 @ W0^T (+ A1 @ W1^T) + bias ), W row-major [OUT,K] bf16.
// 128x128 block tile, BK=32, 4 waves (2x2), 4x4 fragments of 16x16x32 per wave.
// LDS row stride 40 bf16 (80B): frag ds_read_b128 conflict-free (G4 arithmetic).
#define LDSK 40

template <typename TOUT>
__global__ __launch_bounds__(256)
void gemm_mfma(const bf16_t* __restrict__ A0, const bf16_t* __restrict__ W0,
               const bf16_t* __restrict__ A1, const bf16_t* __restrict__ W1,
               const float* __restrict__ bias, const float* __restrict__ bn,
               TOUT* __restrict__ C, int M, int K, int OUT, int dual) {
  __shared__ bf16_t lds[2][(128 + 128) * LDSK];
  const int tid = threadIdx.x;
  const int lane = tid & 63, wid = tid >> 6;
  const int wm = wid >> 1, wn = wid & 1;
  const int row0 = blockIdx.x * 128, col0 = blockIdx.y * 128;
  const int l15 = lane & 15, l4 = lane >> 4;

  const int srow = tid >> 1;        // staging row 0..127
  const int sk = (tid & 1) * 16;    // staging k-offset (bf16) within BK=32

  const int nk = K / 32;
  const int nsteps = dual ? nk * 2 : nk;

  f32x4 acc[4][4] = {};
  uint4 va0, va1, vb0, vb1;

  auto stage_load = [&](int s) {
    const bf16_t* A = (s < nk) ? A0 : A1;
    const bf16_t* W = (s < nk) ? W0 : W1;
    int kk = ((s < nk) ? s : s - nk) * 32 + sk;
    uint4 z; z.x = z.y = z.z = z.w = 0u;
    va0 = z; va1 = z; vb0 = z; vb1 = z;
    int ar = row0 + srow;
    if (ar < M) {
      const uint4* p = reinterpret_cast<const uint4*>(&A[(size_t)ar * K + kk]);
      va0 = p[0]; va1 = p[1];
    }
    int br = col0 + srow;
    if (br < OUT) {
      const uint4* p = reinterpret_cast<const uint4*>(&W[(size_t)br * K + kk]);
      vb0 = p[0]; vb1 = p[1];
    }
  };
  auto stage_write = [&](int b) {
    uint4* la = reinterpret_cast<uint4*>(&lds[b][srow * LDSK + sk]);
    la[0] = va0; la[1] = va1;
    uint4* lb = reinterpret_cast<uint4*>(&lds[b][(128 + srow) * LDSK + sk]);
    lb[0] = vb0; lb[1] = vb1;
  };

  stage_load(0);
  stage_write(0);
  __syncthreads();
  int cur = 0;
  for (int s = 0; s < nsteps; ++s) {
    if (s + 1 < nsteps) stage_load(s + 1);   // global loads overlap MFMA below
    const bf16_t* pa = &lds[cur][(wm * 64 + l15) * LDSK + l4 * 8];
    const bf16_t* pb = &lds[cur][(128 + wn * 64 + l15) * LDSK + l4 * 8];
    bf16x8 a[4], b[4];
#pragma unroll
    for (int i = 0; i < 4; ++i) a[i] = *reinterpret_cast<const bf16x8*>(&pa[i * 16 * LDSK]);
#pragma unroll
    for (int j = 0; j < 4; ++j) b[j] = *reinterpret_cast<const bf16x8*>(&pb[j * 16 * LDSK]);
#pragma unroll
    for (int i = 0; i < 4; ++i)
#pragma unroll
      for (int j = 0; j < 4; ++j)
        acc[i][j] = __builtin_amdgcn_mfma_f32_16x16x32_bf16(a[i], b[j], acc[i][j], 0, 0, 0);
    if (s + 1 < nsteps) {
      stage_write(cur ^ 1);
      __syncthreads();
      cur ^= 1;
    }
  }

  // epilogue: C/D frag mapping col=lane&15, row=(lane>>4)*4+reg  [m89]
#pragma unroll
  for (int j = 0; j < 4; ++j) {
    int col = col0 + wn * 64 + j * 16 + l15;
    if (col >= OUT) continue;
    float bs = bias ? bias[col] : 0.f;
    float scale = 1.f, shift = bs;
    bool has_bn = (bn != nullptr);
    if (has_bn) {
      float g = bn[col], bb = bn[256 + col], mm = bn[512 + col], vv = bn[768 + col];
      float is = g * rsqrtf(vv + BN_EPS);
      scale = is; shift = (bs - mm) * is + bb;
    }
#pragma unroll
    for (int i = 0; i < 4; ++i) {
#pragma unroll
      for (int r = 0; r < 4; ++r) {
        int row = row0 + wm * 64 + i * 16 + l4 * 4 + r;
        if (row >= M) continue;
        float v = acc[i][j][r];
        v = has_bn ? fmaxf(v * scale + shift, 0.f) : (v + bs);
        store1(&C[(size_t)row * OUT + col], v);
      }
    }
  }
}

// ---------------- row log-softmax (C=40) ----------------
__global__ __launch_bounds__(256)
void k_logsoftmax(const float* __restrict__ logits, float* __restrict__ out, int M) {
  int row = blockIdx.x * 4 + (threadIdx.x >> 6);
  if (row >= M) return;
  int lane = threadIdx.x & 63;
  float v = (lane < C_OUT) ? logits[(size_t)row * C_OUT + lane] : -1e30f;
  float m = v;
#pragma unroll
  for (int o = 32; o; o >>= 1) m = fmaxf(m, __shfl_xor(m, o));
  float e = (lane < C_OUT) ? expf(v - m) : 0.f;
  float s = e;
#pragma unroll
  for (int o = 32; o; o >>= 1) s += __shfl_xor(s, o);
  if (lane < C_OUT) out[(size_t)row * C_OUT + lane] = v - m - logf(s);
}

// ---------------- host launch ----------------
extern "C" void kernel_launch(void* const* d_in, const int* in_sizes, int n_in,
                              void* d_out, int out_size, void* d_ws, size_t ws_size,
                              hipStream_t stream) {
  const float* x       = (const float*)d_in[0];
  const int*   ei      = (const int*)d_in[1];   // [2, E] int32
  const float* pre_w   = (const float*)d_in[2];
  const float* pre_b   = (const float*)d_in[3];
  const float* bn      = (const float*)d_in[4]; // [5,4,256]
  const float* lin_l_w = (const float*)d_in[5];
  const float* lin_l_b = (const float*)d_in[6];
  const float* lin_r_w = (const float*)d_in[7];
  const float* post1_w = (const float*)d_in[8];
  const float* post1_b = (const float*)d_in[9];
  const float* post2_w = (const float*)d_in[10];
  const float* post2_b = (const float*)d_in[11];
  float* out = (float*)d_out;

  const int* src = ei;
  const int* dstv = ei + N_EDGES;

  char* base = (char*)d_ws;
  size_t off = 0;
  auto alloc = [&](size_t bytes) -> void* {
    void* p = base + off;
    off = (off + bytes + 255) & ~(size_t)255;
    return p;
  };
  bf16_t* hA = (bf16_t*)alloc((size_t)N_NODES * HDIM * 2);
  bf16_t* hB = (bf16_t*)alloc((size_t)N_NODES * HDIM * 2);  // also x_bf16 pre-GEMM, f32 logits post
  bf16_t* hC = (bf16_t*)alloc((size_t)N_NODES * HDIM * 2);
  int* row_ptr = (int*)alloc((size_t)(N_NODES + 1) * 4);
  int* cursor  = (int*)alloc((size_t)N_NODES * 4);   // doubles as per-node degree after k_rank
  int* csr     = (int*)alloc((size_t)N_EDGES * 4);
  int* rank    = (int*)alloc((size_t)N_EDGES * 4);
  float* inv   = (float*)alloc((size_t)N_NODES * 4);
  int* blk_sum = (int*)alloc(128 * 4);
  int* blk_off = (int*)alloc(128 * 4);
  bf16_t* w_pre = (bf16_t*)alloc((size_t)HDIM * F_INDIM * 2);
  bf16_t* w_ll  = (bf16_t*)alloc((size_t)3 * HDIM * HDIM * 2);
  bf16_t* w_lr  = (bf16_t*)alloc((size_t)3 * HDIM * HDIM * 2);
  bf16_t* w_p1  = (bf16_t*)alloc((size_t)HDIM * HDIM * 2);
  bf16_t* w_p2  = (bf16_t*)alloc((size_t)C_OUT * HDIM * 2);
  (void)n_in; (void)in_sizes; (void)out_size;
  if (off > ws_size) return;  // visible failure (zeros), no fault

  bf16_t* x_bf = hB;

  // weight/input conversions
  {
    int n;
    n = N_NODES * F_INDIM;
    k_cvt<<<(n / 4 + 255) / 256, 256, 0, stream>>>(x, x_bf, n);
    n = HDIM * F_INDIM;
    k_cvt<<<(n / 4 + 255) / 256, 256, 0, stream>>>(pre_w, w_pre, n);
    n = 3 * HDIM * HDIM;
    k_cvt<<<(n / 4 + 255) / 256, 256, 0, stream>>>(lin_l_w, w_ll, n);
    k_cvt<<<(n / 4 + 255) / 256, 256, 0, stream>>>(lin_r_w, w_lr, n);
    n = HDIM * HDIM;
    k_cvt<<<(n / 4 + 255) / 256, 256, 0, stream>>>(post1_w, w_p1, n);
    n = C_OUT * HDIM;
    k_cvt<<<(n / 4 + 255) / 256, 256, 0, stream>>>(post2_w, w_p2, n);
  }

  // CSR build: one atomic pass (rank+hist), scan, atomic-free placement
  hipMemsetAsync(cursor, 0, (size_t)N_NODES * 4, stream);
  k_rank<<<2048, 256, 0, stream>>>(dstv, cursor, rank, N_EDGES);
  int nb = (N_NODES + 1023) / 1024;  // 98
  k_scan_local<<<nb, 1024, 0, stream>>>(cursor, row_ptr, blk_sum, N_NODES);
  k_scan_blk<<<1, 128, 0, stream>>>(blk_sum, blk_off, nb);
  k_scan_add<<<(N_NODES + 255) / 256, 256, 0, stream>>>(row_ptr, blk_off, N_NODES);
  k_place<<<2048, 256, 0, stream>>>(src, dstv, rank, row_ptr, csr, N_EDGES);
  k_inv<<<(N_NODES + 255) / 256, 256, 0, stream>>>(cursor, inv, N_NODES);

  dim3 gH((N_NODES + 127) / 128, 2);   // OUT=256
  // pre: h = relu(bn0(x @ pre_w^T + pre_b))
  gemm_mfma<bf16_t><<<gH, 256, 0, stream>>>(
      x_bf, w_pre, nullptr, nullptr, pre_b, bn, hA, N_NODES, F_INDIM, HDIM, 0);

  bf16_t* hcur = hA;
  bf16_t* hnext = hC;
  for (int i = 0; i < 3; ++i) {
    k_aggregate<<<N_NODES / 4, 256, 0, stream>>>(hcur, row_ptr, csr, inv, hB);
    gemm_mfma<bf16_t><<<gH, 256, 0, stream>>>(
        hB, w_ll + (size_t)i * HDIM * HDIM,
        hcur, w_lr + (size_t)i * HDIM * HDIM,
        lin_l_b + (size_t)i * HDIM,
        bn + (size_t)(i + 1) * 4 * HDIM,
        hnext, N_NODES, HDIM, HDIM, 1);
    bf16_t* t = hcur; hcur = hnext; hnext = t;
  }
  // post1
  gemm_mfma<bf16_t><<<gH, 256, 0, stream>>>(
      hcur, w_p1, nullptr, nullptr, post1_b,
      bn + (size_t)4 * 4 * HDIM, hnext, N_NODES, HDIM, HDIM, 0);
  // post2 -> f32 logits (no bn); hB is free now
  float* logits = (float*)hB;
  dim3 gC((N_NODES + 127) / 128, 1);
  gemm_mfma<float><<<gC, 256, 0, stream>>>(
      hnext, w_p2, nullptr, nullptr, post2_b,
      nullptr, logits, N_NODES, HDIM, C_OUT, 0);
  k_logsoftmax<<<(N_NODES + 3) / 4, 256, 0, stream>>>(logits, out, N_NODES);
}

// Round 9
// 793.967 us; speedup vs baseline: 4.1765x; 1.0244x over previous
//
#include <hip/hip_runtime.h>
#include <cstdint>
#include <cstddef>

#define N_NODES 100000
#define N_EDGES 1600000
#define F_INDIM 128
#define HDIM 256
#define C_OUT 40
#define BN_EPS 1e-5f

typedef unsigned short bf16_t;
typedef __attribute__((ext_vector_type(8))) short bf16x8;
typedef __attribute__((ext_vector_type(4))) float f32x4;

__device__ __forceinline__ float bf2f(unsigned int u) {
  return __uint_as_float(u << 16);
}
__device__ __forceinline__ bf16_t f2bf(float f) {
  unsigned int x = __float_as_uint(f);
  return (bf16_t)((x + 0x7fffu + ((x >> 16) & 1u)) >> 16);
}

// ---------------- f32 -> bf16 conversion (n % 4 == 0) ----------------
__global__ void k_cvt(const float* __restrict__ s, bf16_t* __restrict__ d, int n) {
  int i = (blockIdx.x * blockDim.x + threadIdx.x) * 4;
  if (i >= n) return;
  float4 v = *reinterpret_cast<const float4*>(&s[i]);
  uint2 o;
  o.x = (unsigned)f2bf(v.x) | ((unsigned)f2bf(v.y) << 16);
  o.y = (unsigned)f2bf(v.z) | ((unsigned)f2bf(v.w) << 16);
  *reinterpret_cast<uint2*>(&d[i]) = o;
}

// ---------------- CSR build (merged hist+rank, atomic-free placement) -------
__global__ void k_rank(const int* __restrict__ dst, int* __restrict__ cursor,
                       int* __restrict__ rank, int E) {
  for (int e = blockIdx.x * blockDim.x + threadIdx.x; e < E; e += gridDim.x * blockDim.x)
    rank[e] = atomicAdd(&cursor[dst[e]], 1);
}

__global__ __launch_bounds__(1024)
void k_scan_local(const int* __restrict__ cnt, int* __restrict__ row_ptr,
                  int* __restrict__ blk_sum, int n) {
  __shared__ int buf[1024];
  int tid = threadIdx.x;
  int i = blockIdx.x * 1024 + tid;
  int v = (i < n) ? cnt[i] : 0;
  buf[tid] = v;
  __syncthreads();
  for (int off = 1; off < 1024; off <<= 1) {
    int t = (tid >= off) ? buf[tid - off] : 0;
    __syncthreads();
    buf[tid] += t;
    __syncthreads();
  }
  if (i < n) row_ptr[i] = buf[tid] - v;       // block-local exclusive
  if (tid == 1023) blk_sum[blockIdx.x] = buf[1023];
}

__global__ __launch_bounds__(128)
void k_scan_blk(const int* __restrict__ blk_sum, int* __restrict__ blk_off, int nb) {
  __shared__ int buf[128];
  int tid = threadIdx.x;
  int v = (tid < nb) ? blk_sum[tid] : 0;
  buf[tid] = v;
  __syncthreads();
  for (int off = 1; off < 128; off <<= 1) {
    int t = (tid >= off) ? buf[tid - off] : 0;
    __syncthreads();
    buf[tid] += t;
    __syncthreads();
  }
  if (tid < nb) blk_off[tid] = buf[tid] - v;  // exclusive
}

__global__ void k_scan_add(int* __restrict__ row_ptr, const int* __restrict__ blk_off, int n) {
  int i = blockIdx.x * blockDim.x + threadIdx.x;
  if (i < n) row_ptr[i] += blk_off[i >> 10];
  if (i == 0) row_ptr[n] = N_EDGES;
}

__global__ void k_place(const int* __restrict__ src, const int* __restrict__ dst,
                        const int* __restrict__ rank, const int* __restrict__ row_ptr,
                        int* __restrict__ csr, int E) {
  for (int e = blockIdx.x * blockDim.x + threadIdx.x; e < E; e += gridDim.x * blockDim.x)
    csr[row_ptr[dst[e]] + rank[e]] = src[e];
}

__global__ void k_inv(const int* __restrict__ cnt, float* __restrict__ inv, int n) {
  int i = blockIdx.x * blockDim.x + threadIdx.x;
  if (i < n) inv[i] = 1.0f / (float)(cnt[i] > 0 ? cnt[i] : 1);
}

// ---------------- mean aggregation ----------------
__device__ __forceinline__ void add8(float* acc, uint4 r) {
  acc[0] += bf2f(r.x & 0xffffu); acc[1] += bf2f(r.x >> 16);
  acc[2] += bf2f(r.y & 0xffffu); acc[3] += bf2f(r.y >> 16);
  acc[4] += bf2f(r.z & 0xffffu); acc[5] += bf2f(r.z >> 16);
  acc[6] += bf2f(r.w & 0xffffu); acc[7] += bf2f(r.w >> 16);
}

__global__ __launch_bounds__(256)
void k_aggregate(const bf16_t* __restrict__ h, const int* __restrict__ row_ptr,
                 const int* __restrict__ csr, const float* __restrict__ inv_deg,
                 bf16_t* __restrict__ mean) {
  int w = threadIdx.x >> 6, lane = threadIdx.x & 63;
  int node = blockIdx.x * 4 + w;
  if (node >= N_NODES) return;
  int beg = row_ptr[node], end = row_ptr[node + 1];
  int half = lane >> 5;         // 0 or 1: which edge of the pair
  int l32 = lane & 31;          // 16B column block within the row
  float acc[8] = {};
  int deg = end - beg;
  int p = beg;
  int p8 = beg + (deg & ~7);
  for (; p < p8; p += 8) {       // 8 edges per iteration, 4 row loads/lane in flight
    int s0 = csr[p + half];
    int s1 = csr[p + 2 + half];
    int s2 = csr[p + 4 + half];
    int s3 = csr[p + 6 + half];
    uint4 r0 = *reinterpret_cast<const uint4*>(&h[(size_t)s0 * HDIM + l32 * 8]);
    uint4 r1 = *reinterpret_cast<const uint4*>(&h[(size_t)s1 * HDIM + l32 * 8]);
    uint4 r2 = *reinterpret_cast<const uint4*>(&h[(size_t)s2 * HDIM + l32 * 8]);
    uint4 r3 = *reinterpret_cast<const uint4*>(&h[(size_t)s3 * HDIM + l32 * 8]);
    add8(acc, r0);
    add8(acc, r1);
    add8(acc, r2);
    add8(acc, r3);
  }
  if (end - p >= 4) {            // 4-edge block: 2 row loads in flight
    int s0 = csr[p + half];
    int s1 = csr[p + 2 + half];
    uint4 r0 = *reinterpret_cast<const uint4*>(&h[(size_t)s0 * HDIM + l32 * 8]);
    uint4 r1 = *reinterpret_cast<const uint4*>(&h[(size_t)s1 * HDIM + l32 * 8]);
    add8(acc, r0);
    add8(acc, r1);
    p += 4;
  }
  for (; p < end; p += 2) {      // tail: <=3 edges, pair-guarded
    int e = p + half;
    if (e < end) {
      int s = csr[e];
      uint4 r = *reinterpret_cast<const uint4*>(&h[(size_t)s * HDIM + l32 * 8]);
      add8(acc, r);
    }
  }
#pragma unroll
  for (int k = 0; k < 8; ++k) acc[k] += __shfl_xor(acc[k], 32);
  if (half == 0) {
    float iv = inv_deg[node];
    uint4 o;
    o.x = (unsigned)f2bf(acc[0] * iv) | ((unsigned)f2bf(acc[1] * iv) << 16);
    o.y = (unsigned)f2bf(acc[2] * iv) | ((unsigned)f2bf(acc[3] * iv) << 16);
    o.z = (unsigned)f2bf(acc[4] * iv) | ((unsigned)f2bf(acc[5] * iv) << 16);
    o.w = (unsigned)f2bf(acc[6] * iv) | ((unsigned)f2bf(acc[7] * iv) << 16);
    *reinterpret_cast<uint4*>(&mean[(size_t)node * HDIM + l32 * 8]) = o;
  }
}

// ---------------- output store helpers ----------------
__device__ __forceinline__ void store1(float* p, float v) { *p = v; }
__device__ __forceinline__ void store1(bf16_t* p, float v) { *p = f2bf(v); }

// ---------------- bf16 MFMA GEMM, global_load_lds staging (m97 structure) ---
// C[M,OUT] = act( A0 @ W0^T (+ A1 @ W1^T) + bias ), W row-major [OUT,K] bf16.
// 128x128 tile, BK=32, 4 waves (2x2), 4x4 frags of 16x16x32 per wave.
// LDS: linear [128][32] A and B tiles, double-buffered (32 KB total).
// Staging: global_load_lds 16B/lane — dest is wave-uniform base + lane*16
// (m104), so LDS must be linear in lane order; per-lane GLOBAL address
// matches row = chunk*16 + lane/4, kk = (lane&3)*8.
template <typename TOUT>
__global__ __launch_bounds__(256)
void gemm_mfma(const bf16_t* __restrict__ A0, const bf16_t* __restrict__ W0,
               const bf16_t* __restrict__ A1, const bf16_t* __restrict__ W1,
               const float* __restrict__ bias, const float* __restrict__ bn,
               TOUT* __restrict__ C, int M, int K, int OUT, int dual) {
  __shared__ bf16_t lds[2][2][128 * 32];   // [buf][A/B][row*32+k]
  const int tid = threadIdx.x;
  const int lane = tid & 63, wid = tid >> 6;
  const int wm = wid >> 1, wn = wid & 1;
  const int row0 = blockIdx.x * 128, col0 = blockIdx.y * 128;
  const int l15 = lane & 15, l4 = lane >> 4;

  const int nk = K / 32;
  const int nsteps = dual ? nk * 2 : nk;

  f32x4 acc[4][4] = {};

  // per-lane source coordinates for the two chunks this wave stages
  const int srow_base = wid * 32 + (lane >> 2);  // chunk row for c=0 (chunk=wid*2)
  const int skk = (lane & 3) * 8;                // bf16 elem offset within BK

  auto stage = [&](int s, int b) {
    const bf16_t* A = (s < nk) ? A0 : A1;
    const bf16_t* W = (s < nk) ? W0 : W1;
    int kk0 = ((s < nk) ? s : s - nk) * 32 + skk;
#pragma unroll
    for (int c = 0; c < 2; ++c) {
      int chunk = wid * 2 + c;            // 0..7
      int row = srow_base + c * 16;       // chunk*16 + lane/4
      int ar = row0 + row; if (ar >= M) ar = M - 1;
      int br = col0 + row; if (br >= OUT) br = OUT - 1;
      const bf16_t* gA = &A[(size_t)ar * K + kk0];
      const bf16_t* gB = &W[(size_t)br * K + kk0];
      __builtin_amdgcn_global_load_lds(
          (const __attribute__((address_space(1))) unsigned int*)gA,
          (__attribute__((address_space(3))) unsigned int*)&lds[b][0][chunk * 512],
          16, 0, 0);
      __builtin_amdgcn_global_load_lds(
          (const __attribute__((address_space(1))) unsigned int*)gB,
          (__attribute__((address_space(3))) unsigned int*)&lds[b][1][chunk * 512],
          16, 0, 0);
    }
  };

  stage(0, 0);
  __syncthreads();               // drains vmcnt(0): buffer 0 ready
  int cur = 0;
  for (int s = 0; s < nsteps; ++s) {
    if (s + 1 < nsteps) stage(s + 1, cur ^ 1);   // async into other buffer
    const bf16_t* pa = &lds[cur][0][l15 * 32 + l4 * 8];
    const bf16_t* pb = &lds[cur][1][l15 * 32 + l4 * 8];
    bf16x8 a[4], b[4];
#pragma unroll
    for (int i = 0; i < 4; ++i)
      a[i] = *reinterpret_cast<const bf16x8*>(&pa[(wm * 64 + i * 16) * 32]);
#pragma unroll
    for (int j = 0; j < 4; ++j)
      b[j] = *reinterpret_cast<const bf16x8*>(&pb[(wn * 64 + j * 16) * 32]);
#pragma unroll
    for (int i = 0; i < 4; ++i)
#pragma unroll
      for (int j = 0; j < 4; ++j)
        acc[i][j] = __builtin_amdgcn_mfma_f32_16x16x32_bf16(a[i], b[j], acc[i][j], 0, 0, 0);
    if (s + 1 < nsteps) {
      __syncthreads();           // all reads of cur done AND staged buffer drained
      cur ^= 1;
    }
  }

  // epilogue: C/D frag mapping col=lane&15, row=(lane>>4)*4+reg  [m89]
#pragma unroll
  for (int j = 0; j < 4; ++j) {
    int col = col0 + wn * 64 + j * 16 + l15;
    if (col >= OUT) continue;
    float bs = bias ? bias[col] : 0.f;
    float scale = 1.f, shift = bs;
    bool has_bn = (bn != nullptr);
    if (has_bn) {
      float g = bn[col], bb = bn[256 + col], mm = bn[512 + col], vv = bn[768 + col];
      float is = g * rsqrtf(vv + BN_EPS);
      scale = is; shift = (bs - mm) * is + bb;
    }
#pragma unroll
    for (int i = 0; i < 4; ++i) {
#pragma unroll
      for (int r = 0; r < 4; ++r) {
        int row = row0 + wm * 64 + i * 16 + l4 * 4 + r;
        if (row >= M) continue;
        float v = acc[i][j][r];
        v = has_bn ? fmaxf(v * scale + shift, 0.f) : (v + bs);
        store1(&C[(size_t)row * OUT + col], v);
      }
    }
  }
}

// ---------------- row log-softmax (C=40) ----------------
__global__ __launch_bounds__(256)
void k_logsoftmax(const float* __restrict__ logits, float* __restrict__ out, int M) {
  int row = blockIdx.x * 4 + (threadIdx.x >> 6);
  if (row >= M) return;
  int lane = threadIdx.x & 63;
  float v = (lane < C_OUT) ? logits[(size_t)row * C_OUT + lane] : -1e30f;
  float m = v;
#pragma unroll
  for (int o = 32; o; o >>= 1) m = fmaxf(m, __shfl_xor(m, o));
  float e = (lane < C_OUT) ? expf(v - m) : 0.f;
  float s = e;
#pragma unroll
  for (int o = 32; o; o >>= 1) s += __shfl_xor(s, o);
  if (lane < C_OUT) out[(size_t)row * C_OUT + lane] = v - m - logf(s);
}

// ---------------- host launch ----------------
extern "C" void kernel_launch(void* const* d_in, const int* in_sizes, int n_in,
                              void* d_out, int out_size, void* d_ws, size_t ws_size,
                              hipStream_t stream) {
  const float* x       = (const float*)d_in[0];
  const int*   ei      = (const int*)d_in[1];   // [2, E] int32
  const float* pre_w   = (const float*)d_in[2];
  const float* pre_b   = (const float*)d_in[3];
  const float* bn      = (const float*)d_in[4]; // [5,4,256]
  const float* lin_l_w = (const float*)d_in[5];
  const float* lin_l_b = (const float*)d_in[6];
  const float* lin_r_w = (const float*)d_in[7];
  const float* post1_w = (const float*)d_in[8];
  const float* post1_b = (const float*)d_in[9];
  const float* post2_w = (const float*)d_in[10];
  const float* post2_b = (const float*)d_in[11];
  float* out = (float*)d_out;

  const int* src = ei;
  const int* dstv = ei + N_EDGES;

  char* base = (char*)d_ws;
  size_t off = 0;
  auto alloc = [&](size_t bytes) -> void* {
    void* p = base + off;
    off = (off + bytes + 255) & ~(size_t)255;
    return p;
  };
  bf16_t* hA = (bf16_t*)alloc((size_t)N_NODES * HDIM * 2);
  bf16_t* hB = (bf16_t*)alloc((size_t)N_NODES * HDIM * 2);  // also x_bf16 pre-GEMM, f32 logits post
  bf16_t* hC = (bf16_t*)alloc((size_t)N_NODES * HDIM * 2);
  int* row_ptr = (int*)alloc((size_t)(N_NODES + 1) * 4);
  int* cursor  = (int*)alloc((size_t)N_NODES * 4);   // doubles as per-node degree after k_rank
  int* csr     = (int*)alloc((size_t)N_EDGES * 4);
  int* rank    = (int*)alloc((size_t)N_EDGES * 4);
  float* inv   = (float*)alloc((size_t)N_NODES * 4);
  int* blk_sum = (int*)alloc(128 * 4);
  int* blk_off = (int*)alloc(128 * 4);
  bf16_t* w_pre = (bf16_t*)alloc((size_t)HDIM * F_INDIM * 2);
  bf16_t* w_ll  = (bf16_t*)alloc((size_t)3 * HDIM * HDIM * 2);
  bf16_t* w_lr  = (bf16_t*)alloc((size_t)3 * HDIM * HDIM * 2);
  bf16_t* w_p1  = (bf16_t*)alloc((size_t)HDIM * HDIM * 2);
  bf16_t* w_p2  = (bf16_t*)alloc((size_t)C_OUT * HDIM * 2);
  (void)n_in; (void)in_sizes; (void)out_size;
  if (off > ws_size) return;  // visible failure (zeros), no fault

  bf16_t* x_bf = hB;

  // weight/input conversions
  {
    int n;
    n = N_NODES * F_INDIM;
    k_cvt<<<(n / 4 + 255) / 256, 256, 0, stream>>>(x, x_bf, n);
    n = HDIM * F_INDIM;
    k_cvt<<<(n / 4 + 255) / 256, 256, 0, stream>>>(pre_w, w_pre, n);
    n = 3 * HDIM * HDIM;
    k_cvt<<<(n / 4 + 255) / 256, 256, 0, stream>>>(lin_l_w, w_ll, n);
    k_cvt<<<(n / 4 + 255) / 256, 256, 0, stream>>>(lin_r_w, w_lr, n);
    n = HDIM * HDIM;
    k_cvt<<<(n / 4 + 255) / 256, 256, 0, stream>>>(post1_w, w_p1, n);
    n = C_OUT * HDIM;
    k_cvt<<<(n / 4 + 255) / 256, 256, 0, stream>>>(post2_w, w_p2, n);
  }

  // CSR build: one atomic pass (rank+hist), scan, atomic-free placement
  hipMemsetAsync(cursor, 0, (size_t)N_NODES * 4, stream);
  k_rank<<<2048, 256, 0, stream>>>(dstv, cursor, rank, N_EDGES);
  int nb = (N_NODES + 1023) / 1024;  // 98
  k_scan_local<<<nb, 1024, 0, stream>>>(cursor, row_ptr, blk_sum, N_NODES);
  k_scan_blk<<<1, 128, 0, stream>>>(blk_sum, blk_off, nb);
  k_scan_add<<<(N_NODES + 255) / 256, 256, 0, stream>>>(row_ptr, blk_off, N_NODES);
  k_place<<<2048, 256, 0, stream>>>(src, dstv, rank, row_ptr, csr, N_EDGES);
  k_inv<<<(N_NODES + 255) / 256, 256, 0, stream>>>(cursor, inv, N_NODES);

  dim3 gH((N_NODES + 127) / 128, 2);   // OUT=256
  // pre: h = relu(bn0(x @ pre_w^T + pre_b))
  gemm_mfma<bf16_t><<<gH, 256, 0, stream>>>(
      x_bf, w_pre, nullptr, nullptr, pre_b, bn, hA, N_NODES, F_INDIM, HDIM, 0);

  bf16_t* hcur = hA;
  bf16_t* hnext = hC;
  for (int i = 0; i < 3; ++i) {
    k_aggregate<<<N_NODES / 4, 256, 0, stream>>>(hcur, row_ptr, csr, inv, hB);
    gemm_mfma<bf16_t><<<gH, 256, 0, stream>>>(
        hB, w_ll + (size_t)i * HDIM * HDIM,
        hcur, w_lr + (size_t)i * HDIM * HDIM,
        lin_l_b + (size_t)i * HDIM,
        bn + (size_t)(i + 1) * 4 * HDIM,
        hnext, N_NODES, HDIM, HDIM, 1);
    bf16_t* t = hcur; hcur = hnext; hnext = t;
  }
  // post1
  gemm_mfma<bf16_t><<<gH, 256, 0, stream>>>(
      hcur, w_p1, nullptr, nullptr, post1_b,
      bn + (size_t)4 * 4 * HDIM, hnext, N_NODES, HDIM, HDIM, 0);
  // post2 -> f32 logits (no bn); hB is free now
  float* logits = (float*)hB;
  dim3 gC((N_NODES + 127) / 128, 1);
  gemm_mfma<float><<<gC, 256, 0, stream>>>(
      hnext, w_p2, nullptr, nullptr, post2_b,
      nullptr, logits, N_NODES, HDIM, C_OUT, 0);
  k_logsoftmax<<<(N_NODES + 3) / 4, 256, 0, stream>>>(logits, out, N_NODES);
}